// Round 1
// baseline (1290.691 us; speedup 1.0000x reference)
//
#include <hip/hip_runtime.h>
#include <math.h>

// HoloAttentionV2: x@Wk^T -> phase, x@Wv^T -> v, dual complex cumsum scan over T,
// gated combine -> y, y@Wo^T -> out.
// Shapes: B=2, T=8192, H=16, D=64, HD=1024, D_MODEL=1024.

#define B_SZ 2
#define T_LEN 8192
#define H_N 16
#define D_N 64
#define HD 1024
#define DM 1024

#define NCH 128                 // chunks per chain
#define CH (T_LEN / NCH)        // 64 steps per chunk

// ---------------- fp32 GEMM: C[m,n] = scale * sum_k A[m,k] * W[n,k] ----------------
// A: MxK row-major, W: NxK row-major, C: MxN row-major. M%128==0, N%128==0, K%16==0.
#define BM 128
#define BN 128
#define BK 16

__global__ __launch_bounds__(256, 2) void gemm_abt(
    const float* __restrict__ A, const float* __restrict__ W,
    float* __restrict__ C, int M, int N, int K, float scale)
{
    __shared__ float As[BK][BM + 4];   // +4 pad keeps rows 16B-aligned (132*4=528=33*16)
    __shared__ float Bs[BK][BN + 4];

    const int tid = threadIdx.x;
    const int m0 = blockIdx.y * BM;
    const int n0 = blockIdx.x * BN;
    const int tx = tid & 15;    // n-direction
    const int ty = tid >> 4;    // m-direction

    float acc[8][8];
#pragma unroll
    for (int i = 0; i < 8; ++i)
#pragma unroll
        for (int j = 0; j < 8; ++j) acc[i][j] = 0.f;

    for (int k0 = 0; k0 < K; k0 += BK) {
        // 512 float4 slots per operand tile; each thread loads slot tid and tid+256
#pragma unroll
        for (int s = 0; s < 2; ++s) {
            int slot = tid + s * 256;
            int row = slot >> 2;
            int kq = (slot & 3) << 2;
            float4 av = *reinterpret_cast<const float4*>(
                &A[(size_t)(m0 + row) * K + k0 + kq]);
            As[kq + 0][row] = av.x; As[kq + 1][row] = av.y;
            As[kq + 2][row] = av.z; As[kq + 3][row] = av.w;
            float4 bv = *reinterpret_cast<const float4*>(
                &W[(size_t)(n0 + row) * K + k0 + kq]);
            Bs[kq + 0][row] = bv.x; Bs[kq + 1][row] = bv.y;
            Bs[kq + 2][row] = bv.z; Bs[kq + 3][row] = bv.w;
        }
        __syncthreads();
#pragma unroll
        for (int k = 0; k < BK; ++k) {
            float a[8], b[8];
#pragma unroll
            for (int i = 0; i < 8; ++i) a[i] = As[k][ty * 8 + i];
#pragma unroll
            for (int j = 0; j < 8; ++j) b[j] = Bs[k][tx * 8 + j];
#pragma unroll
            for (int i = 0; i < 8; ++i)
#pragma unroll
                for (int j = 0; j < 8; ++j)
                    acc[i][j] = fmaf(a[i], b[j], acc[i][j]);
        }
        __syncthreads();
    }

#pragma unroll
    for (int i = 0; i < 8; ++i) {
        size_t r = (size_t)(m0 + ty * 8 + i) * N + n0 + tx * 8;
#pragma unroll
        for (int jq = 0; jq < 2; ++jq) {
            float4 o;
            o.x = scale * acc[i][jq * 4 + 0];
            o.y = scale * acc[i][jq * 4 + 1];
            o.z = scale * acc[i][jq * 4 + 2];
            o.w = scale * acc[i][jq * 4 + 3];
            *reinterpret_cast<float4*>(&C[r + jq * 4]) = o;
        }
    }
}

// ---------------- scan helpers ----------------
// chain = (b,h,d); chunked two-level scan. One 64-lane wave per (b,h,chunk), lane = d.
// gw = ((b*H + h)*NCH + c).  cs layout: 4 planes [B][H][NCH][D]: sp_re, sp_im, sa_re, sa_im.

__device__ __forceinline__ void rotor_sincos(int t, double fd, float* sr, float* cr)
{
    // angle = t*f computed in f64 with explicit mod-2pi reduction (t*f reaches ~5e4 rad
    // where f32 ULP ~4e-3; f64 keeps us within eps of the np reference).
    const double twopi = 6.283185307179586;
    const double inv2pi = 0.15915494309189535;
    double ang = (double)t * fd;
    double n = rint(ang * inv2pi);
    float red = (float)(ang - n * twopi);
    __sincosf(red, sr, cr);  // |red| <= pi: fast path is accurate here
}

__global__ __launch_bounds__(256) void scan_pass1(
    const float* __restrict__ vArr, const float* __restrict__ phase,
    float* __restrict__ cs)
{
    int gw = (blockIdx.x * 256 + threadIdx.x) >> 6;
    int d = threadIdx.x & 63;
    int c = gw & (NCH - 1);
    int h = (gw >> 7) & (H_N - 1);
    int b = gw >> 11;

    double fd = 6.283185307179586 * ((double)(h + 1) / 16.0)
              * pow(10000.0, -(double)d / 64.0);

    int t0 = c * CH;
    size_t base = ((size_t)b * T_LEN + t0) * HD + (size_t)h * D_N + d;

    float cp = 0.f, spv = 0.f;   // cos/sin of phase[t-1]; zero => k_shifted[0] == 0
    if (t0 > 0) {
        float thp = phase[base - HD];
        sincosf(thp, &spv, &cp);
    }

    float sp_re = 0.f, sp_im = 0.f, sa_re = 0.f, sa_im = 0.f;
    for (int i = 0; i < CH; ++i) {
        int t = t0 + i;
        size_t idx = base + (size_t)i * HD;
        float v = vArr[idx];
        float th = phase[idx];
        float cr, sr;
        rotor_sincos(t, fd, &sr, &cr);
        sp_re = fmaf(v, cr, sp_re);
        sp_im = fmaf(v, sr, sp_im);
        sa_re = fmaf(v, cp, sa_re);      // v * conj(k[t-1]) : re = v*cos
        sa_im = fmaf(-v, spv, sa_im);    //                   im = -v*sin
        sincosf(th, &spv, &cp);          // becomes prev for next t
    }

    const size_t NT = (size_t)B_SZ * H_N * NCH * D_N;
    size_t ci = (size_t)gw * D_N + d;
    cs[ci] = sp_re;
    cs[NT + ci] = sp_im;
    cs[2 * NT + ci] = sa_re;
    cs[3 * NT + ci] = sa_im;
}

__global__ void scan_pass2(float* __restrict__ cs)
{
    int tid = blockIdx.x * blockDim.x + threadIdx.x;  // 0..2047
    if (tid >= B_SZ * H_N * D_N) return;
    int d = tid & 63;
    int bh = tid >> 6;
    size_t base = (size_t)bh * NCH * D_N + d;
    const size_t NT = (size_t)B_SZ * H_N * NCH * D_N;
    float r0 = 0.f, r1 = 0.f, r2 = 0.f, r3 = 0.f;
    for (int c = 0; c < NCH; ++c) {
        size_t i = base + (size_t)c * D_N;
        float a = cs[i], b2 = cs[NT + i], c2 = cs[2 * NT + i], d2 = cs[3 * NT + i];
        cs[i] = r0; cs[NT + i] = r1; cs[2 * NT + i] = r2; cs[3 * NT + i] = r3;
        r0 += a; r1 += b2; r2 += c2; r3 += d2;
    }
}

__global__ __launch_bounds__(256) void scan_pass3(
    const float* __restrict__ vArr, const float* __restrict__ phase,
    const float* __restrict__ cs, const float* __restrict__ gate,
    float* __restrict__ y)
{
    int gw = (blockIdx.x * 256 + threadIdx.x) >> 6;
    int d = threadIdx.x & 63;
    int c = gw & (NCH - 1);
    int h = (gw >> 7) & (H_N - 1);
    int b = gw >> 11;

    double fd = 6.283185307179586 * ((double)(h + 1) / 16.0)
              * pow(10000.0, -(double)d / 64.0);
    float g0 = gate[h * 2 + 0];
    float g1 = gate[h * 2 + 1];

    int t0 = c * CH;
    size_t base = ((size_t)b * T_LEN + t0) * HD + (size_t)h * D_N + d;

    const size_t NT = (size_t)B_SZ * H_N * NCH * D_N;
    size_t ci = (size_t)gw * D_N + d;
    float ap_re = cs[ci];
    float ap_im = cs[NT + ci];
    float aa_re = cs[2 * NT + ci];
    float aa_im = cs[3 * NT + ci];

    float cp = 0.f, spv = 0.f;
    if (t0 > 0) {
        float thp = phase[base - HD];
        sincosf(thp, &spv, &cp);
    }

    for (int i = 0; i < CH; ++i) {
        int t = t0 + i;
        size_t idx = base + (size_t)i * HD;
        float v = vArr[idx];
        float th = phase[idx];
        float cr, sr;
        rotor_sincos(t, fd, &sr, &cr);
        ap_re = fmaf(v, cr, ap_re);
        ap_im = fmaf(v, sr, ap_im);
        aa_re = fmaf(v, cp, aa_re);
        aa_im = fmaf(-v, spv, aa_im);
        // out_pos = Re(mem_pos * conj(rotor)) = ap_re*cr + ap_im*sr
        float op = fmaf(ap_re, cr, ap_im * sr);
        float ck, sk;
        sincosf(th, &sk, &ck);
        // out_assoc = Re(mem_assoc * k[t]) = aa_re*ck - aa_im*sk
        float oa = fmaf(aa_re, ck, -aa_im * sk);
        float sc = rsqrtf((float)(t + 1));
        y[idx] = (g0 * op + g1 * oa) * sc;
        cp = ck; spv = sk;
    }
}

// ---------------- launch ----------------
extern "C" void kernel_launch(void* const* d_in, const int* in_sizes, int n_in,
                              void* d_out, int out_size, void* d_ws, size_t ws_size,
                              hipStream_t stream)
{
    const float* x    = (const float*)d_in[0];
    const float* Wk   = (const float*)d_in[1];
    const float* Wv   = (const float*)d_in[2];
    const float* Wo   = (const float*)d_in[3];
    const float* gate = (const float*)d_in[4];
    float* out = (float*)d_out;

    const size_t NE = (size_t)B_SZ * T_LEN * HD;   // 16,777,216 elements

    // phase lives in d_out (dead before the final GEMM overwrites d_out).
    float* phase = (float*)d_out;
    float* vArr = (float*)d_ws;          // NE floats
    float* y    = vArr + NE;             // NE floats
    float* cs   = y + NE;                // 4 * B*H*NCH*D floats (4 MiB)
    // total ws use: 2*64MiB + 4MiB = 132 MiB

    const int M = B_SZ * T_LEN;          // 16384
    dim3 gblk(256);
    dim3 ggrid(HD / BN, M / BM);         // (8, 128)

    // phase = 10 * (x @ Wk^T)
    hipLaunchKernelGGL(gemm_abt, ggrid, gblk, 0, stream, x, Wk, phase, M, HD, DM, 10.0f);
    // v = x @ Wv^T
    hipLaunchKernelGGL(gemm_abt, ggrid, gblk, 0, stream, x, Wv, vArr, M, HD, DM, 1.0f);

    const int waves = B_SZ * H_N * NCH;  // 4096 waves
    hipLaunchKernelGGL(scan_pass1, dim3(waves / 4), dim3(256), 0, stream, vArr, phase, cs);
    hipLaunchKernelGGL(scan_pass2, dim3(8), dim3(256), 0, stream, cs);
    hipLaunchKernelGGL(scan_pass3, dim3(waves / 4), dim3(256), 0, stream, vArr, phase, cs, gate, y);

    // out = y @ Wo^T   (overwrites phase/d_out)
    hipLaunchKernelGGL(gemm_abt, ggrid, gblk, 0, stream, y, Wo, out, M, DM, HD, 1.0f);
}

// Round 2
// 434.750 us; speedup vs baseline: 2.9688x; 2.9688x over previous
//
#include <hip/hip_runtime.h>
#include <math.h>

// HoloAttentionV2 on MI355X.
// Pipeline: convert x/weights to bf16 (x and 10*Wk split hi/lo for precision),
// MFMA GEMMs: phase = x@(10Wk)^T (split, 2 calls), v = x@Wv^T (bf16 out),
// 3-pass chunked complex scan over T, y (bf16), out = y@Wo^T (f32).
// Shapes: B=2, T=8192, H=16, D=64, HD=1024, DM=1024.

#define B_SZ 2
#define T_LEN 8192
#define H_N 16
#define D_N 64
#define HD 1024
#define DM 1024

#define NCH 128                 // chunks per chain
#define CH (T_LEN / NCH)        // 64 steps per chunk

typedef unsigned short u16;
typedef __attribute__((ext_vector_type(4))) unsigned short u16x4;
typedef __attribute__((ext_vector_type(8))) short s16x8;   // 8 bf16 in 4 VGPR
typedef __attribute__((ext_vector_type(4))) float f32x4;

__device__ __forceinline__ u16 f2bf(float f) {
    union { float f; unsigned u; } v; v.f = f;
    unsigned r = v.u + 0x7fffu + ((v.u >> 16) & 1u);   // RNE
    return (u16)(r >> 16);
}
__device__ __forceinline__ float bf2f(u16 h) {
    union { unsigned u; float f; } v; v.u = ((unsigned)h) << 16;
    return v.f;
}

// ---------------- conversion kernels ----------------
__global__ __launch_bounds__(256) void conv_x_split(
    const float* __restrict__ x, u16* __restrict__ xs)
{
    size_t i = ((size_t)blockIdx.x * 256 + threadIdx.x) * 4;
    float4 v = *reinterpret_cast<const float4*>(&x[i]);
    int row = (int)(i >> 10);
    int col = (int)(i & 1023);
    float f[4] = {v.x, v.y, v.z, v.w};
    u16x4 hi, lo;
#pragma unroll
    for (int j = 0; j < 4; ++j) {
        u16 h = f2bf(f[j]);
        hi[j] = h;
        lo[j] = f2bf(f[j] - bf2f(h));
    }
    *reinterpret_cast<u16x4*>(&xs[(size_t)row * 2048 + col]) = hi;
    *reinterpret_cast<u16x4*>(&xs[(size_t)row * 2048 + 1024 + col]) = lo;
}

__global__ __launch_bounds__(256) void conv_wk(
    const float* __restrict__ Wk, u16* __restrict__ Wk2, u16* __restrict__ Wklo)
{
    size_t i = ((size_t)blockIdx.x * 256 + threadIdx.x) * 4;
    float4 v = *reinterpret_cast<const float4*>(&Wk[i]);
    int row = (int)(i >> 10);
    int col = (int)(i & 1023);
    float f[4] = {10.f * v.x, 10.f * v.y, 10.f * v.z, 10.f * v.w}; // fold PHASE_SCALE
    u16x4 hi, lo;
#pragma unroll
    for (int j = 0; j < 4; ++j) {
        u16 h = f2bf(f[j]);
        hi[j] = h;
        lo[j] = f2bf(f[j] - bf2f(h));
    }
    *reinterpret_cast<u16x4*>(&Wk2[(size_t)row * 2048 + col]) = hi;
    *reinterpret_cast<u16x4*>(&Wk2[(size_t)row * 2048 + 1024 + col]) = hi;
    *reinterpret_cast<u16x4*>(&Wklo[(size_t)row * 1024 + col]) = lo;
}

__global__ __launch_bounds__(256) void conv_w(
    const float* __restrict__ W, u16* __restrict__ Wb)
{
    size_t i = ((size_t)blockIdx.x * 256 + threadIdx.x) * 4;
    float4 v = *reinterpret_cast<const float4*>(&W[i]);
    float f[4] = {v.x, v.y, v.z, v.w};
    u16x4 hi;
#pragma unroll
    for (int j = 0; j < 4; ++j) hi[j] = f2bf(f[j]);
    *reinterpret_cast<u16x4*>(&Wb[i]) = hi;
}

// ---------------- bf16 MFMA GEMM: C[m,n] = sum_k A[m,k]*W[n,k] ----------------
// 128x128 tile, BK=64, 4 waves (2x2), each wave 64x64 = 4x4 MFMA frags.
// mode: 0 = f32 store, 1 = f32 accumulate, 2 = bf16 store.
#define GBM 128
#define GBN 128
#define GBK 64

__global__ __launch_bounds__(256, 2) void gemm_mfma(
    const u16* __restrict__ A, int lda, const u16* __restrict__ W, int ldw,
    void* __restrict__ Cv, int ldc, int K, int mode)
{
    __shared__ u16 sA[GBM][GBK];   // 16 KB, row-major, 1KB per 8 rows
    __shared__ u16 sB[GBN][GBK];   // 16 KB

    const int tid  = threadIdx.x;
    const int lane = tid & 63;
    const int wid  = tid >> 6;       // 0..3
    const int wm   = wid >> 1;       // wave row (m) 0..1
    const int wn   = wid & 1;        // wave col (n) 0..1
    const int m0 = blockIdx.y * GBM;
    const int n0 = blockIdx.x * GBN;

    f32x4 acc[4][4] = {};

    // staging: 16 chunks of 1KB per tile; wave w handles chunks 4w..4w+3.
    // chunk c = rows c*8..c*8+7. lane l -> row c*8 + (l>>3), col (l&7)*8 elems.
    const int srow = lane >> 3;
    const int scol = (lane & 7) * 8;

    for (int k0 = 0; k0 < K; k0 += GBK) {
#pragma unroll
        for (int c = 0; c < 4; ++c) {
            const int chunk = wid * 4 + c;
            const int row = chunk * 8 + srow;
            const u16* ga = A + (size_t)(m0 + row) * lda + k0 + scol;
            __builtin_amdgcn_global_load_lds(
                (const __attribute__((address_space(1))) void*)ga,
                (__attribute__((address_space(3))) void*)&sA[chunk * 8][0],
                16, 0, 0);
            const u16* gb = W + (size_t)(n0 + row) * ldw + k0 + scol;
            __builtin_amdgcn_global_load_lds(
                (const __attribute__((address_space(1))) void*)gb,
                (__attribute__((address_space(3))) void*)&sB[chunk * 8][0],
                16, 0, 0);
        }
        __syncthreads();   // drains vmcnt(0) then barrier: tile resident

#pragma unroll
        for (int kk = 0; kk < 2; ++kk) {
            const int kcol = kk * 32 + (lane >> 4) * 8;
            s16x8 af[4], bf[4];
#pragma unroll
            for (int mi = 0; mi < 4; ++mi)
                af[mi] = *reinterpret_cast<const s16x8*>(
                    &sA[wm * 64 + mi * 16 + (lane & 15)][kcol]);
#pragma unroll
            for (int ni = 0; ni < 4; ++ni)
                bf[ni] = *reinterpret_cast<const s16x8*>(
                    &sB[wn * 64 + ni * 16 + (lane & 15)][kcol]);
#pragma unroll
            for (int mi = 0; mi < 4; ++mi)
#pragma unroll
                for (int ni = 0; ni < 4; ++ni)
                    acc[mi][ni] = __builtin_amdgcn_mfma_f32_16x16x32_bf16(
                        af[mi], bf[ni], acc[mi][ni], 0, 0, 0);
        }
        __syncthreads();
    }

    // epilogue: C/D layout col=lane&15, row=(lane>>4)*4+r
    float* Cf = (float*)Cv;
    u16*   Ch = (u16*)Cv;
#pragma unroll
    for (int mi = 0; mi < 4; ++mi) {
#pragma unroll
        for (int ni = 0; ni < 4; ++ni) {
            const int r0  = m0 + wm * 64 + mi * 16 + ((lane >> 4) << 2);
            const int col = n0 + wn * 64 + ni * 16 + (lane & 15);
#pragma unroll
            for (int r = 0; r < 4; ++r) {
                const size_t off = (size_t)(r0 + r) * ldc + col;
                const float val = acc[mi][ni][r];
                if (mode == 0)      Cf[off] = val;
                else if (mode == 1) Cf[off] += val;
                else                Ch[off] = f2bf(val);
            }
        }
    }
}

// ---------------- scan (unchanged math from round 1; v,y now bf16) ----------------
__device__ __forceinline__ void rotor_sincos(int t, double fd, float* sr, float* cr)
{
    const double twopi = 6.283185307179586;
    const double inv2pi = 0.15915494309189535;
    double ang = (double)t * fd;
    double n = rint(ang * inv2pi);
    float red = (float)(ang - n * twopi);
    __sincosf(red, sr, cr);
}

__global__ __launch_bounds__(256) void scan_pass1(
    const u16* __restrict__ vArr, const float* __restrict__ phase,
    float* __restrict__ cs)
{
    int gw = (blockIdx.x * 256 + threadIdx.x) >> 6;
    int d = threadIdx.x & 63;
    int c = gw & (NCH - 1);
    int h = (gw >> 7) & (H_N - 1);
    int b = gw >> 11;

    double fd = 6.283185307179586 * ((double)(h + 1) / 16.0)
              * pow(10000.0, -(double)d / 64.0);

    int t0 = c * CH;
    size_t base = ((size_t)b * T_LEN + t0) * HD + (size_t)h * D_N + d;

    float cp = 0.f, spv = 0.f;
    if (t0 > 0) {
        float thp = phase[base - HD];
        sincosf(thp, &spv, &cp);
    }

    float sp_re = 0.f, sp_im = 0.f, sa_re = 0.f, sa_im = 0.f;
    for (int i = 0; i < CH; ++i) {
        int t = t0 + i;
        size_t idx = base + (size_t)i * HD;
        float v = bf2f(vArr[idx]);
        float th = phase[idx];
        float cr, sr;
        rotor_sincos(t, fd, &sr, &cr);
        sp_re = fmaf(v, cr, sp_re);
        sp_im = fmaf(v, sr, sp_im);
        sa_re = fmaf(v, cp, sa_re);
        sa_im = fmaf(-v, spv, sa_im);
        sincosf(th, &spv, &cp);
    }

    const size_t NT = (size_t)B_SZ * H_N * NCH * D_N;
    size_t ci = (size_t)gw * D_N + d;
    cs[ci] = sp_re;
    cs[NT + ci] = sp_im;
    cs[2 * NT + ci] = sa_re;
    cs[3 * NT + ci] = sa_im;
}

__global__ void scan_pass2(float* __restrict__ cs)
{
    int tid = blockIdx.x * blockDim.x + threadIdx.x;
    if (tid >= B_SZ * H_N * D_N) return;
    int d = tid & 63;
    int bh = tid >> 6;
    size_t base = (size_t)bh * NCH * D_N + d;
    const size_t NT = (size_t)B_SZ * H_N * NCH * D_N;
    float r0 = 0.f, r1 = 0.f, r2 = 0.f, r3 = 0.f;
    for (int c = 0; c < NCH; ++c) {
        size_t i = base + (size_t)c * D_N;
        float a = cs[i], b2 = cs[NT + i], c2 = cs[2 * NT + i], d2 = cs[3 * NT + i];
        cs[i] = r0; cs[NT + i] = r1; cs[2 * NT + i] = r2; cs[3 * NT + i] = r3;
        r0 += a; r1 += b2; r2 += c2; r3 += d2;
    }
}

__global__ __launch_bounds__(256) void scan_pass3(
    const u16* __restrict__ vArr, const float* __restrict__ phase,
    const float* __restrict__ cs, const float* __restrict__ gate,
    u16* __restrict__ y)
{
    int gw = (blockIdx.x * 256 + threadIdx.x) >> 6;
    int d = threadIdx.x & 63;
    int c = gw & (NCH - 1);
    int h = (gw >> 7) & (H_N - 1);
    int b = gw >> 11;

    double fd = 6.283185307179586 * ((double)(h + 1) / 16.0)
              * pow(10000.0, -(double)d / 64.0);
    float g0 = gate[h * 2 + 0];
    float g1 = gate[h * 2 + 1];

    int t0 = c * CH;
    size_t base = ((size_t)b * T_LEN + t0) * HD + (size_t)h * D_N + d;

    const size_t NT = (size_t)B_SZ * H_N * NCH * D_N;
    size_t ci = (size_t)gw * D_N + d;
    float ap_re = cs[ci];
    float ap_im = cs[NT + ci];
    float aa_re = cs[2 * NT + ci];
    float aa_im = cs[3 * NT + ci];

    float cp = 0.f, spv = 0.f;
    if (t0 > 0) {
        float thp = phase[base - HD];
        sincosf(thp, &spv, &cp);
    }

    for (int i = 0; i < CH; ++i) {
        int t = t0 + i;
        size_t idx = base + (size_t)i * HD;
        float v = bf2f(vArr[idx]);
        float th = phase[idx];
        float cr, sr;
        rotor_sincos(t, fd, &sr, &cr);
        ap_re = fmaf(v, cr, ap_re);
        ap_im = fmaf(v, sr, ap_im);
        aa_re = fmaf(v, cp, aa_re);
        aa_im = fmaf(-v, spv, aa_im);
        float op = fmaf(ap_re, cr, ap_im * sr);
        float ck, sk;
        sincosf(th, &sk, &ck);
        float oa = fmaf(aa_re, ck, -aa_im * sk);
        float sc = rsqrtf((float)(t + 1));
        y[idx] = f2bf((g0 * op + g1 * oa) * sc);
        cp = ck; spv = sk;
    }
}

// ---------------- launch ----------------
extern "C" void kernel_launch(void* const* d_in, const int* in_sizes, int n_in,
                              void* d_out, int out_size, void* d_ws, size_t ws_size,
                              hipStream_t stream)
{
    const float* x    = (const float*)d_in[0];
    const float* Wk   = (const float*)d_in[1];
    const float* Wv   = (const float*)d_in[2];
    const float* Wo   = (const float*)d_in[3];
    const float* gate = (const float*)d_in[4];
    float* out = (float*)d_out;

    // phase lives in d_out (dead before the final GEMM overwrites it).
    float* phase = (float*)d_out;

    // ws layout (byte offsets):
    //   0      : xs   [16384][2048] bf16 = 64 MB   (hi | lo)  -- yb aliases it later
    //   64 MB  : vb   [16384][1024] bf16 = 32 MB
    //   96 MB  : cs   4 planes * 2*16*128*64 f32   = 16 MB
    //   112 MB : Wk2  [1024][2048] bf16 = 4 MB     (10*Wk hi | hi)
    //   116 MB : Wklo [1024][1024] bf16 = 2 MB
    //   118 MB : Wvb  2 MB
    //   120 MB : Wob  2 MB                         total 122 MB
    char* wsb = (char*)d_ws;
    u16*   xs   = (u16*)wsb;
    u16*   yb   = (u16*)wsb;                        // alias: xs dead after v-GEMM
    u16*   vb   = (u16*)(wsb + (64ull << 20));
    float* cs   = (float*)(wsb + (96ull << 20));
    u16*   Wk2  = (u16*)(wsb + (112ull << 20));
    u16*   Wklo = (u16*)(wsb + (116ull << 20));
    u16*   Wvb  = (u16*)(wsb + (118ull << 20));
    u16*   Wob  = (u16*)(wsb + (120ull << 20));

    // conversions
    hipLaunchKernelGGL(conv_x_split, dim3(16384), dim3(256), 0, stream, x, xs);
    hipLaunchKernelGGL(conv_wk, dim3(1024), dim3(256), 0, stream, Wk, Wk2, Wklo);
    hipLaunchKernelGGL(conv_w,  dim3(1024), dim3(256), 0, stream, Wv, Wvb);
    hipLaunchKernelGGL(conv_w,  dim3(1024), dim3(256), 0, stream, Wo, Wob);

    const dim3 gblk(256);
    const dim3 ggrid(HD / GBN, (B_SZ * T_LEN) / GBM);   // (8, 128)

    // phase = [xhi|xlo]@[10Wk_hi|10Wk_hi]^T  (K=2048, f32 store)
    hipLaunchKernelGGL(gemm_mfma, ggrid, gblk, 0, stream,
                       xs, 2048, Wk2, 2048, (void*)phase, HD, 2048, 0);
    // phase += xhi@10Wk_lo^T                 (K=1024, f32 accumulate)
    hipLaunchKernelGGL(gemm_mfma, ggrid, gblk, 0, stream,
                       xs, 2048, Wklo, 1024, (void*)phase, HD, 1024, 1);
    // vb = bf16(xhi@Wv^T)                    (K=1024, bf16 store)
    hipLaunchKernelGGL(gemm_mfma, ggrid, gblk, 0, stream,
                       xs, 2048, Wvb, 1024, (void*)vb, HD, 1024, 2);

    const int waves = B_SZ * H_N * NCH;   // 4096
    hipLaunchKernelGGL(scan_pass1, dim3(waves / 4), dim3(256), 0, stream, vb, phase, cs);
    hipLaunchKernelGGL(scan_pass2, dim3(8), dim3(256), 0, stream, cs);
    hipLaunchKernelGGL(scan_pass3, dim3(waves / 4), dim3(256), 0, stream, vb, phase, cs, gate, yb);

    // out = yb@Wo^T  (overwrites phase in d_out)
    hipLaunchKernelGGL(gemm_mfma, ggrid, gblk, 0, stream,
                       yb, 1024, Wob, 1024, (void*)out, HD, 1024, 0);
}

// Round 3
// 356.428 us; speedup vs baseline: 3.6212x; 1.2197x over previous
//
#include <hip/hip_runtime.h>
#include <math.h>

// HoloAttentionV2 on MI355X (gfx950).
// bf16 MFMA GEMMs (m97-structure: 128x128 tile, BK=32, global_load_lds w16,
// XCD-swizzled blocks), phase computed as single K=3072 split-bf16 GEMM via
// A-column wrap, 3-pass chunked complex scan with rotor recurrence.
// Shapes: B=2, T=8192, H=16, D=64, HD=1024, DM=1024.

#define B_SZ 2
#define T_LEN 8192
#define H_N 16
#define D_N 64
#define HD 1024
#define DM 1024

#define NCH 128                 // chunks per chain
#define CH (T_LEN / NCH)        // 64 steps per chunk

typedef unsigned short u16;
typedef __attribute__((ext_vector_type(4))) unsigned short u16x4;
typedef __attribute__((ext_vector_type(8))) short s16x8;   // 8 bf16 in 4 VGPR
typedef __attribute__((ext_vector_type(4))) float f32x4;

__device__ __forceinline__ u16 f2bf(float f) {
    union { float f; unsigned u; } v; v.f = f;
    unsigned r = v.u + 0x7fffu + ((v.u >> 16) & 1u);   // RNE
    return (u16)(r >> 16);
}
__device__ __forceinline__ float bf2f(u16 h) {
    union { unsigned u; float f; } v; v.u = ((unsigned)h) << 16;
    return v.f;
}

// ---------------- conversion kernels ----------------
__global__ __launch_bounds__(256) void conv_x_split(
    const float* __restrict__ x, u16* __restrict__ xs)
{
    size_t i = ((size_t)blockIdx.x * 256 + threadIdx.x) * 4;
    float4 v = *reinterpret_cast<const float4*>(&x[i]);
    int row = (int)(i >> 10);
    int col = (int)(i & 1023);
    float f[4] = {v.x, v.y, v.z, v.w};
    u16x4 hi, lo;
#pragma unroll
    for (int j = 0; j < 4; ++j) {
        u16 h = f2bf(f[j]);
        hi[j] = h;
        lo[j] = f2bf(f[j] - bf2f(h));
    }
    *reinterpret_cast<u16x4*>(&xs[(size_t)row * 2048 + col]) = hi;
    *reinterpret_cast<u16x4*>(&xs[(size_t)row * 2048 + 1024 + col]) = lo;
}

// Wk3 = [10Wk_hi | 10Wk_hi | 10Wk_lo]  (pairs with A cols [hi | lo | hi-wrap])
__global__ __launch_bounds__(256) void conv_wk(
    const float* __restrict__ Wk, u16* __restrict__ Wk3)
{
    size_t i = ((size_t)blockIdx.x * 256 + threadIdx.x) * 4;
    float4 v = *reinterpret_cast<const float4*>(&Wk[i]);
    int row = (int)(i >> 10);
    int col = (int)(i & 1023);
    float f[4] = {10.f * v.x, 10.f * v.y, 10.f * v.z, 10.f * v.w};
    u16x4 hi, lo;
#pragma unroll
    for (int j = 0; j < 4; ++j) {
        u16 h = f2bf(f[j]);
        hi[j] = h;
        lo[j] = f2bf(f[j] - bf2f(h));
    }
    *reinterpret_cast<u16x4*>(&Wk3[(size_t)row * 3072 + col]) = hi;
    *reinterpret_cast<u16x4*>(&Wk3[(size_t)row * 3072 + 1024 + col]) = hi;
    *reinterpret_cast<u16x4*>(&Wk3[(size_t)row * 3072 + 2048 + col]) = lo;
}

__global__ __launch_bounds__(256) void conv_w(
    const float* __restrict__ W, u16* __restrict__ Wb)
{
    size_t i = ((size_t)blockIdx.x * 256 + threadIdx.x) * 4;
    float4 v = *reinterpret_cast<const float4*>(&W[i]);
    float f[4] = {v.x, v.y, v.z, v.w};
    u16x4 hi;
#pragma unroll
    for (int j = 0; j < 4; ++j) hi[j] = f2bf(f[j]);
    *reinterpret_cast<u16x4*>(&Wb[i]) = hi;
}

// ---------------- bf16 MFMA GEMM (m97 structure) ----------------
// C[m,n] = sum_k A[m, wrap(k)] * W[n, k];  128x128 tile, BK=32, 4 waves 2x2,
// each wave 64x64 = 4x4 MFMA frags. mode: 0 = f32 store, 2 = bf16 store.
#define GBM 128
#define GBN 128
#define GBK 32

__global__ __launch_bounds__(256) void gemm_mfma(
    const u16* __restrict__ A, int lda, const u16* __restrict__ W, int ldw,
    void* __restrict__ Cv, int ldc, int K, int kwrapA, int mode)
{
    __shared__ u16 sA[GBM][GBK];   // 8 KB, 64 B rows
    __shared__ u16 sB[GBN][GBK];   // 8 KB

    const int tid  = threadIdx.x;
    const int lane = tid & 63;
    const int wid  = tid >> 6;       // 0..3
    const int wm   = wid >> 1;
    const int wn   = wid & 1;

    // XCD-aware chunked swizzle (nwg = 8*128 = 1024, divisible by 8)
    const int nbx = gridDim.x;
    const int flat = blockIdx.y * nbx + blockIdx.x;
    const int total = nbx * gridDim.y;
    const int cpx = total >> 3;
    const int swz = (flat & 7) * cpx + (flat >> 3);
    const int bx = swz % nbx;
    const int by = swz / nbx;
    const int m0 = by * GBM;
    const int n0 = bx * GBN;

    f32x4 acc[4][4] = {};

    // staging: tile = 8 KB = 8 chunks of 1 KB; wave w handles chunks w, w+4.
    // chunk c covers rows c*16..c*16+15; lane l -> row c*16 + (l>>2), col (l&3)*8.
    const int srow = lane >> 2;
    const int scol = (lane & 3) * 8;

    for (int k0 = 0; k0 < K; k0 += GBK) {
        const int ka = (k0 < kwrapA) ? k0 : k0 - kwrapA;
#pragma unroll
        for (int s = 0; s < 2; ++s) {
            const int c = wid + s * 4;
            const int row = c * 16 + srow;
            const u16* ga = A + (size_t)(m0 + row) * lda + ka + scol;
            __builtin_amdgcn_global_load_lds(
                (const __attribute__((address_space(1))) void*)ga,
                (__attribute__((address_space(3))) void*)&sA[c * 16][0],
                16, 0, 0);
            const u16* gb = W + (size_t)(n0 + row) * ldw + k0 + scol;
            __builtin_amdgcn_global_load_lds(
                (const __attribute__((address_space(1))) void*)gb,
                (__attribute__((address_space(3))) void*)&sB[c * 16][0],
                16, 0, 0);
        }
        __syncthreads();   // drains vmcnt(0): tile resident for all waves

        {
            const int kcol = (lane >> 4) * 8;
            s16x8 af[4], bf[4];
#pragma unroll
            for (int mi = 0; mi < 4; ++mi)
                af[mi] = *reinterpret_cast<const s16x8*>(
                    &sA[wm * 64 + mi * 16 + (lane & 15)][kcol]);
#pragma unroll
            for (int ni = 0; ni < 4; ++ni)
                bf[ni] = *reinterpret_cast<const s16x8*>(
                    &sB[wn * 64 + ni * 16 + (lane & 15)][kcol]);
#pragma unroll
            for (int mi = 0; mi < 4; ++mi)
#pragma unroll
                for (int ni = 0; ni < 4; ++ni)
                    acc[mi][ni] = __builtin_amdgcn_mfma_f32_16x16x32_bf16(
                        af[mi], bf[ni], acc[mi][ni], 0, 0, 0);
        }
        __syncthreads();
    }

    // epilogue: C/D layout col=lane&15, row=(lane>>4)*4+r
    float* Cf = (float*)Cv;
    u16*   Ch = (u16*)Cv;
#pragma unroll
    for (int mi = 0; mi < 4; ++mi) {
#pragma unroll
        for (int ni = 0; ni < 4; ++ni) {
            const int r0  = m0 + wm * 64 + mi * 16 + ((lane >> 4) << 2);
            const int col = n0 + wn * 64 + ni * 16 + (lane & 15);
#pragma unroll
            for (int r = 0; r < 4; ++r) {
                const size_t off = (size_t)(r0 + r) * ldc + col;
                const float val = acc[mi][ni][r];
                if (mode == 0) Cf[off] = val;
                else           Ch[off] = f2bf(val);
            }
        }
    }
}

// ---------------- scan ----------------
// chain = (b,h,d); one 64-lane wave per (b,h,chunk), lane = d.
// Rotor at t = t0 seeded in f64 (mod-2pi), stepped by e^{i*f} recurrence (64 steps).
__device__ __forceinline__ void rotor_sincos(int t, double fd, float* sr, float* cr)
{
    const double twopi = 6.283185307179586;
    const double inv2pi = 0.15915494309189535;
    double ang = (double)t * fd;
    double n = rint(ang * inv2pi);
    float red = (float)(ang - n * twopi);
    __sincosf(red, sr, cr);
}

__global__ __launch_bounds__(256) void scan_pass1(
    const u16* __restrict__ vArr, const float* __restrict__ phase,
    float* __restrict__ cs)
{
    int gw = (blockIdx.x * 256 + threadIdx.x) >> 6;
    int d = threadIdx.x & 63;
    int c = gw & (NCH - 1);
    int h = (gw >> 7) & (H_N - 1);
    int b = gw >> 11;

    double fd = 6.283185307179586 * ((double)(h + 1) / 16.0)
              * pow(10000.0, -(double)d / 64.0);

    int t0 = c * CH;
    size_t base = ((size_t)b * T_LEN + t0) * HD + (size_t)h * D_N + d;

    float cr, sr;                       // rotor(t)
    rotor_sincos(t0, fd, &sr, &cr);
    float cf, sf;                       // rotor step e^{i*fd}
    sincosf((float)fd, &sf, &cf);

    float cp = 0.f, spv = 0.f;          // k[t-1]; zero => k_shifted[0]==0
    if (t0 > 0) {
        float thp = phase[base - HD];
        __sincosf(thp, &spv, &cp);
    }

    float sp_re = 0.f, sp_im = 0.f, sa_re = 0.f, sa_im = 0.f;
    for (int i = 0; i < CH; ++i) {
        size_t idx = base + (size_t)i * HD;
        float v = bf2f(vArr[idx]);
        float th = phase[idx];
        sp_re = fmaf(v, cr, sp_re);
        sp_im = fmaf(v, sr, sp_im);
        sa_re = fmaf(v, cp, sa_re);
        sa_im = fmaf(-v, spv, sa_im);
        __sincosf(th, &spv, &cp);       // k[t] becomes prev
        float nc = fmaf(cr, cf, -sr * sf);
        float ns = fmaf(sr, cf,  cr * sf);
        cr = nc; sr = ns;
    }

    const size_t NT = (size_t)B_SZ * H_N * NCH * D_N;
    size_t ci = (size_t)gw * D_N + d;
    cs[ci] = sp_re;
    cs[NT + ci] = sp_im;
    cs[2 * NT + ci] = sa_re;
    cs[3 * NT + ci] = sa_im;
}

__global__ void scan_pass2(float* __restrict__ cs)
{
    int tid = blockIdx.x * blockDim.x + threadIdx.x;
    if (tid >= B_SZ * H_N * D_N) return;
    int d = tid & 63;
    int bh = tid >> 6;
    size_t base = (size_t)bh * NCH * D_N + d;
    const size_t NT = (size_t)B_SZ * H_N * NCH * D_N;
    float r0 = 0.f, r1 = 0.f, r2 = 0.f, r3 = 0.f;
    for (int c = 0; c < NCH; ++c) {
        size_t i = base + (size_t)c * D_N;
        float a = cs[i], b2 = cs[NT + i], c2 = cs[2 * NT + i], d2 = cs[3 * NT + i];
        cs[i] = r0; cs[NT + i] = r1; cs[2 * NT + i] = r2; cs[3 * NT + i] = r3;
        r0 += a; r1 += b2; r2 += c2; r3 += d2;
    }
}

__global__ __launch_bounds__(256) void scan_pass3(
    const u16* __restrict__ vArr, const float* __restrict__ phase,
    const float* __restrict__ cs, const float* __restrict__ gate,
    u16* __restrict__ y)
{
    int gw = (blockIdx.x * 256 + threadIdx.x) >> 6;
    int d = threadIdx.x & 63;
    int c = gw & (NCH - 1);
    int h = (gw >> 7) & (H_N - 1);
    int b = gw >> 11;

    double fd = 6.283185307179586 * ((double)(h + 1) / 16.0)
              * pow(10000.0, -(double)d / 64.0);
    float g0 = gate[h * 2 + 0];
    float g1 = gate[h * 2 + 1];

    int t0 = c * CH;
    size_t base = ((size_t)b * T_LEN + t0) * HD + (size_t)h * D_N + d;

    const size_t NT = (size_t)B_SZ * H_N * NCH * D_N;
    size_t ci = (size_t)gw * D_N + d;
    float ap_re = cs[ci];
    float ap_im = cs[NT + ci];
    float aa_re = cs[2 * NT + ci];
    float aa_im = cs[3 * NT + ci];

    float cr, sr;
    rotor_sincos(t0, fd, &sr, &cr);
    float cf, sf;
    sincosf((float)fd, &sf, &cf);

    float cp = 0.f, spv = 0.f;
    if (t0 > 0) {
        float thp = phase[base - HD];
        __sincosf(thp, &spv, &cp);
    }

    for (int i = 0; i < CH; ++i) {
        int t = t0 + i;
        size_t idx = base + (size_t)i * HD;
        float v = bf2f(vArr[idx]);
        float th = phase[idx];
        ap_re = fmaf(v, cr, ap_re);
        ap_im = fmaf(v, sr, ap_im);
        aa_re = fmaf(v, cp, aa_re);
        aa_im = fmaf(-v, spv, aa_im);
        float op = fmaf(ap_re, cr, ap_im * sr);     // Re(mem_pos * conj(rotor))
        float ck, sk;
        __sincosf(th, &sk, &ck);
        float oa = fmaf(aa_re, ck, -aa_im * sk);    // Re(mem_assoc * k[t])
        float sc = rsqrtf((float)(t + 1));
        y[idx] = f2bf((g0 * op + g1 * oa) * sc);
        cp = ck; spv = sk;
        float nc = fmaf(cr, cf, -sr * sf);
        float ns = fmaf(sr, cf,  cr * sf);
        cr = nc; sr = ns;
    }
}

// ---------------- launch ----------------
extern "C" void kernel_launch(void* const* d_in, const int* in_sizes, int n_in,
                              void* d_out, int out_size, void* d_ws, size_t ws_size,
                              hipStream_t stream)
{
    const float* x    = (const float*)d_in[0];
    const float* Wk   = (const float*)d_in[1];
    const float* Wv   = (const float*)d_in[2];
    const float* Wo   = (const float*)d_in[3];
    const float* gate = (const float*)d_in[4];
    float* out = (float*)d_out;

    // phase lives in d_out (dead before the final GEMM overwrites it).
    float* phase = (float*)d_out;

    // ws layout (MiB offsets):
    //   0   : xs   [16384][2048] bf16 (hi|lo) = 64   -- yb aliases it later
    //   64  : vb   [16384][1024] bf16        = 32
    //   96  : cs   4 * 2*16*128*64 f32       = 4
    //   100 : Wk3  [1024][3072] bf16         = 6
    //   106 : Wvb                              2
    //   108 : Wob                              2     total 110 MiB
    char* wsb = (char*)d_ws;
    u16*   xs  = (u16*)wsb;
    u16*   yb  = (u16*)wsb;                       // alias: xs dead after v-GEMM
    u16*   vb  = (u16*)(wsb + (64ull << 20));
    float* cs  = (float*)(wsb + (96ull << 20));
    u16*   Wk3 = (u16*)(wsb + (100ull << 20));
    u16*   Wvb = (u16*)(wsb + (106ull << 20));
    u16*   Wob = (u16*)(wsb + (108ull << 20));

    hipLaunchKernelGGL(conv_x_split, dim3(16384), dim3(256), 0, stream, x, xs);
    hipLaunchKernelGGL(conv_wk, dim3(1024), dim3(256), 0, stream, Wk, Wk3);
    hipLaunchKernelGGL(conv_w,  dim3(1024), dim3(256), 0, stream, Wv, Wvb);
    hipLaunchKernelGGL(conv_w,  dim3(1024), dim3(256), 0, stream, Wo, Wob);

    const dim3 gblk(256);
    const dim3 ggrid(HD / GBN, (B_SZ * T_LEN) / GBM);   // (8, 128)

    // phase = xhi@10Wkhi^T + xlo@10Wkhi^T + xhi@10Wklo^T  (K=3072, A wraps at 2048)
    hipLaunchKernelGGL(gemm_mfma, ggrid, gblk, 0, stream,
                       xs, 2048, Wk3, 3072, (void*)phase, HD, 3072, 2048, 0);
    // vb = bf16(xhi@Wv^T)
    hipLaunchKernelGGL(gemm_mfma, ggrid, gblk, 0, stream,
                       xs, 2048, Wvb, 1024, (void*)vb, HD, 1024, 1024, 2);

    const int waves = B_SZ * H_N * NCH;   // 4096
    hipLaunchKernelGGL(scan_pass1, dim3(waves / 4), dim3(256), 0, stream, vb, phase, cs);
    hipLaunchKernelGGL(scan_pass2, dim3(8), dim3(256), 0, stream, cs);
    hipLaunchKernelGGL(scan_pass3, dim3(waves / 4), dim3(256), 0, stream, vb, phase, cs, gate, yb);

    // out = yb@Wo^T  (overwrites phase in d_out)
    hipLaunchKernelGGL(gemm_mfma, ggrid, gblk, 0, stream,
                       yb, 1024, Wob, 1024, (void*)out, HD, 1024, 1024, 0);
}

// Round 4
// 251.062 us; speedup vs baseline: 5.1409x; 1.4197x over previous
//
#include <hip/hip_runtime.h>
#include <math.h>

// HoloAttentionV2 on MI355X (gfx950).
// 256x256 8-phase bf16 MFMA GEMM (T1 XCD-swizzle + T2 LDS XOR-swizzle +
// T3/T4 counted-vmcnt pipeline + T5 setprio), split-bf16 K=3072 phase GEMM,
// 3-pass chunked complex scan.
// Shapes: B=2, T=8192, H=16, D=64, HD=1024, DM=1024.

#define B_SZ 2
#define T_LEN 8192
#define H_N 16
#define D_N 64
#define HD 1024
#define DM 1024

#define NCH 128                 // chunks per chain
#define CH (T_LEN / NCH)        // 64 steps per chunk

typedef unsigned short u16;
typedef __attribute__((ext_vector_type(4))) unsigned short u16x4;
typedef __attribute__((ext_vector_type(8))) short s16x8;   // 8 bf16 in 4 VGPR
typedef __attribute__((ext_vector_type(4))) float f32x4;

__device__ __forceinline__ u16 f2bf(float f) {
    union { float f; unsigned u; } v; v.f = f;
    unsigned r = v.u + 0x7fffu + ((v.u >> 16) & 1u);   // RNE
    return (u16)(r >> 16);
}
__device__ __forceinline__ float bf2f(u16 h) {
    union { unsigned u; float f; } v; v.u = ((unsigned)h) << 16;
    return v.f;
}

// ---------------- conversion kernels ----------------
__global__ __launch_bounds__(256) void conv_x_split(
    const float* __restrict__ x, u16* __restrict__ xs)
{
    size_t i = ((size_t)blockIdx.x * 256 + threadIdx.x) * 4;
    float4 v = *reinterpret_cast<const float4*>(&x[i]);
    int row = (int)(i >> 10);
    int col = (int)(i & 1023);
    float f[4] = {v.x, v.y, v.z, v.w};
    u16x4 hi, lo;
#pragma unroll
    for (int j = 0; j < 4; ++j) {
        u16 h = f2bf(f[j]);
        hi[j] = h;
        lo[j] = f2bf(f[j] - bf2f(h));
    }
    *reinterpret_cast<u16x4*>(&xs[(size_t)row * 2048 + col]) = hi;
    *reinterpret_cast<u16x4*>(&xs[(size_t)row * 2048 + 1024 + col]) = lo;
}

// Wk3 = [10Wk_hi | 10Wk_hi | 10Wk_lo]  (pairs with A cols [hi | lo | hi-wrap])
__global__ __launch_bounds__(256) void conv_wk(
    const float* __restrict__ Wk, u16* __restrict__ Wk3)
{
    size_t i = ((size_t)blockIdx.x * 256 + threadIdx.x) * 4;
    float4 v = *reinterpret_cast<const float4*>(&Wk[i]);
    int row = (int)(i >> 10);
    int col = (int)(i & 1023);
    float f[4] = {10.f * v.x, 10.f * v.y, 10.f * v.z, 10.f * v.w};
    u16x4 hi, lo;
#pragma unroll
    for (int j = 0; j < 4; ++j) {
        u16 h = f2bf(f[j]);
        hi[j] = h;
        lo[j] = f2bf(f[j] - bf2f(h));
    }
    *reinterpret_cast<u16x4*>(&Wk3[(size_t)row * 3072 + col]) = hi;
    *reinterpret_cast<u16x4*>(&Wk3[(size_t)row * 3072 + 1024 + col]) = hi;
    *reinterpret_cast<u16x4*>(&Wk3[(size_t)row * 3072 + 2048 + col]) = lo;
}

__global__ __launch_bounds__(256) void conv_w(
    const float* __restrict__ W, u16* __restrict__ Wb)
{
    size_t i = ((size_t)blockIdx.x * 256 + threadIdx.x) * 4;
    float4 v = *reinterpret_cast<const float4*>(&W[i]);
    float f[4] = {v.x, v.y, v.z, v.w};
    u16x4 hi;
#pragma unroll
    for (int j = 0; j < 4; ++j) hi[j] = f2bf(f[j]);
    *reinterpret_cast<u16x4*>(&Wb[i]) = hi;
}

// ---------------- 256x256 8-phase bf16 MFMA GEMM ----------------
// C[m,n] = sum_k A[m, wrap(k)] * W[n, k]. 512 threads = 8 waves (2M x 4N),
// per-wave 128x64 output = 8x4 frags of 16x16. BK=64, double-buffered LDS
// (128 KiB): buf b at b*65536: A[256][64] then B[256][64], bf16,
// XOR-swizzled: byte_in_row ^= (row&7)<<4.
#define GBK 64

#define BAR()   asm volatile("s_barrier" ::: "memory")
#define VMCNT4() asm volatile("s_waitcnt vmcnt(4)" ::: "memory")
#define VMCNT0() asm volatile("s_waitcnt vmcnt(0)" ::: "memory")

#define MFMA_Q(mh, nh)                                               \
  {                                                                  \
    __builtin_amdgcn_s_setprio(1);                                   \
    _Pragma("unroll")                                                \
    for (int ks_ = 0; ks_ < 2; ++ks_)                                \
      _Pragma("unroll")                                              \
      for (int m_ = 0; m_ < 4; ++m_)                                 \
        _Pragma("unroll")                                            \
        for (int n_ = 0; n_ < 2; ++n_)                               \
          acc[(mh)*4 + m_][(nh)*2 + n_] =                            \
            __builtin_amdgcn_mfma_f32_16x16x32_bf16(                 \
              aR[m_][ks_], bR[(nh)*2 + n_][ks_],                     \
              acc[(mh)*4 + m_][(nh)*2 + n_], 0, 0, 0);               \
    __builtin_amdgcn_s_setprio(0);                                   \
  }

__device__ __forceinline__ s16x8 rd16(const char* base, int row, int cb) {
    return *reinterpret_cast<const s16x8*>(
        base + row * 128 + (cb ^ ((row & 7) << 4)));
}

// Stage one half-tile (128 rows x 64 cols bf16 = 16 KB) via global_load_lds.
// LDS dest linear (wave-uniform base + lane*16); global src pre-inverse-swizzled.
__device__ __forceinline__ void stage_half(
    const u16* __restrict__ g, int ld, int rowbase, int kbase,
    char* ldshalf, int wid, int lane)
{
#pragma unroll
    for (int s = 0; s < 2; ++s) {
        const int slot = s * 512 + wid * 64 + lane;
        const int r = slot >> 3;
        const int cb = ((slot & 7) << 4) ^ ((r & 7) << 4);
        const u16* gp = g + (size_t)(rowbase + r) * ld + kbase + (cb >> 1);
        __builtin_amdgcn_global_load_lds(
            (const __attribute__((address_space(1))) void*)gp,
            (__attribute__((address_space(3))) void*)(ldshalf + s * 8192 + wid * 1024),
            16, 0, 0);
    }
}

__global__ __launch_bounds__(512, 2) void gemm_mfma256(
    const u16* __restrict__ A, int lda, const u16* __restrict__ W, int ldw,
    void* __restrict__ Cv, int ldc, int K, int kwrapA, int mode)
{
    __shared__ __align__(16) char lds[131072];

    const int tid  = threadIdx.x;
    const int lane = tid & 63;
    const int wid  = tid >> 6;      // 0..7
    const int wm   = wid >> 2;      // 0..1
    const int wn   = wid & 3;       // 0..3
    const int l15  = lane & 15;
    const int hib  = (lane >> 4) << 4;   // byte offset within k-slot row chunk

    // XCD-aware chunked swizzle (total = 256, divisible by 8)
    const int nbx = gridDim.x;
    const int flat = blockIdx.y * nbx + blockIdx.x;
    const int total = nbx * gridDim.y;
    const int cpx = total >> 3;
    const int swz = (flat & 7) * cpx + (flat >> 3);
    const int m0 = (swz / nbx) * 256;
    const int n0 = (swz % nbx) * 256;

    const int NK2 = K / (2 * GBK);

    f32x4 acc[8][4] = {};
    s16x8 aR[4][2], bR[4][2];

    // stage target helpers: A half h of ktile kt -> buf: lds[buf*65536 + h*16384]
    //                       B half h of ktile kt -> buf: +32768
    auto STAGE_A = [&](int kt, int buf, int h) {
        const int kb = kt * GBK;
        const int ka = (kb < kwrapA) ? kb : kb - kwrapA;
        stage_half(A, lda, m0 + h * 128, ka,
                   (char*)lds + buf * 65536 + h * 16384, wid, lane);
    };
    auto STAGE_B = [&](int kt, int buf, int h) {
        stage_half(W, ldw, n0 + h * 128, kt * GBK,
                   (char*)lds + buf * 65536 + 32768 + h * 16384, wid, lane);
    };

    // prologue: ktile0 -> buf0 (B0,B1,A0,A1); ktile1 -> buf1 (B0,B1)
    STAGE_B(0, 0, 0); STAGE_B(0, 0, 1);
    STAGE_A(0, 0, 0); STAGE_A(0, 0, 1);
    STAGE_B(1, 1, 0); STAGE_B(1, 1, 1);
    VMCNT4();         // drain ktile0's 4 half-tiles; ktile1.B in flight
    BAR();

    for (int t = 0; t < NK2; ++t) {
        const bool gm = (t < NK2 - 1);
#pragma unroll
        for (int ph = 0; ph < 2; ++ph) {
            const char* ldsA = (const char*)lds + ph * 65536;
            const char* ldsB = (const char*)lds + ph * 65536 + 32768;
            // ---- phase 1: q(0,0); stage A-half0 of next A-target ----
#pragma unroll
            for (int ks = 0; ks < 2; ++ks) {
#pragma unroll
                for (int m = 0; m < 4; ++m)
                    aR[m][ks] = rd16(ldsA, wm * 128 + m * 16 + l15, ks * 64 + hib);
#pragma unroll
                for (int n = 0; n < 2; ++n)
                    bR[n][ks] = rd16(ldsB, wn * 64 + n * 16 + l15, ks * 64 + hib);
            }
            if (ph == 0)      STAGE_A(2 * t + 1, 1, 0);
            else if (gm)      STAGE_A(2 * t + 2, 0, 0);
            BAR();
            MFMA_Q(0, 0);
            BAR();
            // ---- phase 2: q(0,1); stage A-half1 ----
#pragma unroll
            for (int ks = 0; ks < 2; ++ks)
#pragma unroll
                for (int n = 0; n < 2; ++n)
                    bR[2 + n][ks] = rd16(ldsB, wn * 64 + (2 + n) * 16 + l15, ks * 64 + hib);
            if (ph == 0)      STAGE_A(2 * t + 1, 1, 1);
            else if (gm)      STAGE_A(2 * t + 2, 0, 1);
            BAR();
            MFMA_Q(0, 1);
            BAR();
            // ---- phase 3: q(1,0); stage B-half0 of ktile 2t+2+ph ----
#pragma unroll
            for (int ks = 0; ks < 2; ++ks)
#pragma unroll
                for (int m = 0; m < 4; ++m)
                    aR[m][ks] = rd16(ldsA, wm * 128 + 64 + m * 16 + l15, ks * 64 + hib);
            if (gm) STAGE_B(2 * t + 2 + ph, ph, 0);
            BAR();
            MFMA_Q(1, 0);
            BAR();
            // ---- phase 4: q(1,1); stage B-half1; counted vmcnt ----
            if (gm) {
                STAGE_B(2 * t + 2 + ph, ph, 1);
                VMCNT4();
            } else {
                VMCNT0();
            }
            BAR();
            MFMA_Q(1, 1);
            BAR();
        }
    }

    // epilogue: C/D layout col=lane&15, row=(lane>>4)*4+r per 16x16 frag
    float* Cf = (float*)Cv;
    u16*   Ch = (u16*)Cv;
#pragma unroll
    for (int m = 0; m < 8; ++m) {
#pragma unroll
        for (int n = 0; n < 4; ++n) {
            const int r0  = m0 + wm * 128 + m * 16 + ((lane >> 4) << 2);
            const int col = n0 + wn * 64 + n * 16 + l15;
#pragma unroll
            for (int r = 0; r < 4; ++r) {
                const size_t off = (size_t)(r0 + r) * ldc + col;
                const float val = acc[m][n][r];
                if (mode == 0) Cf[off] = val;
                else           Ch[off] = f2bf(val);
            }
        }
    }
}

// ---------------- scan ----------------
__device__ __forceinline__ void rotor_sincos(int t, double fd, float* sr, float* cr)
{
    const double twopi = 6.283185307179586;
    const double inv2pi = 0.15915494309189535;
    double ang = (double)t * fd;
    double n = rint(ang * inv2pi);
    float red = (float)(ang - n * twopi);
    __sincosf(red, sr, cr);
}

__global__ __launch_bounds__(256) void scan_pass1(
    const u16* __restrict__ vArr, const float* __restrict__ phase,
    float* __restrict__ cs)
{
    int gw = (blockIdx.x * 256 + threadIdx.x) >> 6;
    int d = threadIdx.x & 63;
    int c = gw & (NCH - 1);
    int h = (gw >> 7) & (H_N - 1);
    int b = gw >> 11;

    double fd = 6.283185307179586 * ((double)(h + 1) / 16.0)
              * pow(10000.0, -(double)d / 64.0);

    int t0 = c * CH;
    size_t base = ((size_t)b * T_LEN + t0) * HD + (size_t)h * D_N + d;

    float cr, sr;
    rotor_sincos(t0, fd, &sr, &cr);
    float cf, sf;
    sincosf((float)fd, &sf, &cf);

    float cp = 0.f, spv = 0.f;
    if (t0 > 0) {
        float thp = phase[base - HD];
        __sincosf(thp, &spv, &cp);
    }

    float sp_re = 0.f, sp_im = 0.f, sa_re = 0.f, sa_im = 0.f;
    for (int i = 0; i < CH; ++i) {
        size_t idx = base + (size_t)i * HD;
        float v = bf2f(vArr[idx]);
        float th = phase[idx];
        sp_re = fmaf(v, cr, sp_re);
        sp_im = fmaf(v, sr, sp_im);
        sa_re = fmaf(v, cp, sa_re);
        sa_im = fmaf(-v, spv, sa_im);
        __sincosf(th, &spv, &cp);
        float nc = fmaf(cr, cf, -sr * sf);
        float ns = fmaf(sr, cf,  cr * sf);
        cr = nc; sr = ns;
    }

    const size_t NT = (size_t)B_SZ * H_N * NCH * D_N;
    size_t ci = (size_t)gw * D_N + d;
    cs[ci] = sp_re;
    cs[NT + ci] = sp_im;
    cs[2 * NT + ci] = sa_re;
    cs[3 * NT + ci] = sa_im;
}

__global__ void scan_pass2(float* __restrict__ cs)
{
    int tid = blockIdx.x * blockDim.x + threadIdx.x;
    if (tid >= B_SZ * H_N * D_N) return;
    int d = tid & 63;
    int bh = tid >> 6;
    size_t base = (size_t)bh * NCH * D_N + d;
    const size_t NT = (size_t)B_SZ * H_N * NCH * D_N;
    float r0 = 0.f, r1 = 0.f, r2 = 0.f, r3 = 0.f;
    for (int c = 0; c < NCH; ++c) {
        size_t i = base + (size_t)c * D_N;
        float a = cs[i], b2 = cs[NT + i], c2 = cs[2 * NT + i], d2 = cs[3 * NT + i];
        cs[i] = r0; cs[NT + i] = r1; cs[2 * NT + i] = r2; cs[3 * NT + i] = r3;
        r0 += a; r1 += b2; r2 += c2; r3 += d2;
    }
}

__global__ __launch_bounds__(256) void scan_pass3(
    const u16* __restrict__ vArr, const float* __restrict__ phase,
    const float* __restrict__ cs, const float* __restrict__ gate,
    u16* __restrict__ y)
{
    int gw = (blockIdx.x * 256 + threadIdx.x) >> 6;
    int d = threadIdx.x & 63;
    int c = gw & (NCH - 1);
    int h = (gw >> 7) & (H_N - 1);
    int b = gw >> 11;

    double fd = 6.283185307179586 * ((double)(h + 1) / 16.0)
              * pow(10000.0, -(double)d / 64.0);
    float g0 = gate[h * 2 + 0];
    float g1 = gate[h * 2 + 1];

    int t0 = c * CH;
    size_t base = ((size_t)b * T_LEN + t0) * HD + (size_t)h * D_N + d;

    const size_t NT = (size_t)B_SZ * H_N * NCH * D_N;
    size_t ci = (size_t)gw * D_N + d;
    float ap_re = cs[ci];
    float ap_im = cs[NT + ci];
    float aa_re = cs[2 * NT + ci];
    float aa_im = cs[3 * NT + ci];

    float cr, sr;
    rotor_sincos(t0, fd, &sr, &cr);
    float cf, sf;
    sincosf((float)fd, &sf, &cf);

    float cp = 0.f, spv = 0.f;
    if (t0 > 0) {
        float thp = phase[base - HD];
        __sincosf(thp, &spv, &cp);
    }

    for (int i = 0; i < CH; ++i) {
        int t = t0 + i;
        size_t idx = base + (size_t)i * HD;
        float v = bf2f(vArr[idx]);
        float th = phase[idx];
        ap_re = fmaf(v, cr, ap_re);
        ap_im = fmaf(v, sr, ap_im);
        aa_re = fmaf(v, cp, aa_re);
        aa_im = fmaf(-v, spv, aa_im);
        float op = fmaf(ap_re, cr, ap_im * sr);
        float ck, sk;
        __sincosf(th, &sk, &ck);
        float oa = fmaf(aa_re, ck, -aa_im * sk);
        float sc = rsqrtf((float)(t + 1));
        y[idx] = f2bf((g0 * op + g1 * oa) * sc);
        cp = ck; spv = sk;
        float nc = fmaf(cr, cf, -sr * sf);
        float ns = fmaf(sr, cf,  cr * sf);
        cr = nc; sr = ns;
    }
}

// ---------------- launch ----------------
extern "C" void kernel_launch(void* const* d_in, const int* in_sizes, int n_in,
                              void* d_out, int out_size, void* d_ws, size_t ws_size,
                              hipStream_t stream)
{
    const float* x    = (const float*)d_in[0];
    const float* Wk   = (const float*)d_in[1];
    const float* Wv   = (const float*)d_in[2];
    const float* Wo   = (const float*)d_in[3];
    const float* gate = (const float*)d_in[4];
    float* out = (float*)d_out;

    // phase lives in d_out (dead before the final GEMM overwrites it).
    float* phase = (float*)d_out;

    // ws layout (MiB offsets):
    //   0   : xs   [16384][2048] bf16 (hi|lo) = 64   -- yb aliases it later
    //   64  : vb   [16384][1024] bf16        = 32
    //   96  : cs   4 * 2*16*128*64 f32       = 4
    //   100 : Wk3  [1024][3072] bf16         = 6
    //   106 : Wvb                              2
    //   108 : Wob                              2     total 110 MiB
    char* wsb = (char*)d_ws;
    u16*   xs  = (u16*)wsb;
    u16*   yb  = (u16*)wsb;                       // alias: xs dead after v-GEMM
    u16*   vb  = (u16*)(wsb + (64ull << 20));
    float* cs  = (float*)(wsb + (96ull << 20));
    u16*   Wk3 = (u16*)(wsb + (100ull << 20));
    u16*   Wvb = (u16*)(wsb + (106ull << 20));
    u16*   Wob = (u16*)(wsb + (108ull << 20));

    hipLaunchKernelGGL(conv_x_split, dim3(16384), dim3(256), 0, stream, x, xs);
    hipLaunchKernelGGL(conv_wk, dim3(1024), dim3(256), 0, stream, Wk, Wk3);
    hipLaunchKernelGGL(conv_w,  dim3(1024), dim3(256), 0, stream, Wv, Wvb);
    hipLaunchKernelGGL(conv_w,  dim3(1024), dim3(256), 0, stream, Wo, Wob);

    const dim3 gblk(512);
    const dim3 ggrid(HD / 256, (B_SZ * T_LEN) / 256);   // (4, 64) = 256 blocks

    // phase = xhi@10Wkhi^T + xlo@10Wkhi^T + xhi@10Wklo^T  (K=3072, A wraps at 2048)
    hipLaunchKernelGGL(gemm_mfma256, ggrid, gblk, 0, stream,
                       xs, 2048, Wk3, 3072, (void*)phase, HD, 3072, 2048, 0);
    // vb = bf16(xhi@Wv^T)
    hipLaunchKernelGGL(gemm_mfma256, ggrid, gblk, 0, stream,
                       xs, 2048, Wvb, 1024, (void*)vb, HD, 1024, 1 << 30, 2);

    const int waves = B_SZ * H_N * NCH;   // 4096
    hipLaunchKernelGGL(scan_pass1, dim3(waves / 4), dim3(256), 0, stream, vb, phase, cs);
    hipLaunchKernelGGL(scan_pass2, dim3(8), dim3(256), 0, stream, cs);
    hipLaunchKernelGGL(scan_pass3, dim3(waves / 4), dim3(256), 0, stream, vb, phase, cs, gate, yb);

    // out = yb@Wo^T  (overwrites phase in d_out)
    hipLaunchKernelGGL(gemm_mfma256, ggrid, gblk, 0, stream,
                       yb, 1024, Wob, 1024, (void*)out, HD, 1024, 1 << 30, 0);
}

// Round 5
// 247.959 us; speedup vs baseline: 5.2053x; 1.0125x over previous
//
#include <hip/hip_runtime.h>
#include <math.h>

// HoloAttentionV2 on MI355X (gfx950).
// 256x256 8-phase bf16 MFMA GEMM with inline-asm ds_read_b128 + manual
// lgkmcnt/sched_barrier (rule #18 discipline), counted vmcnt pipeline,
// XCD-aware 2-col-major block order. Split-bf16 K=3072 phase GEMM,
// 3-pass chunked complex scan.
// Shapes: B=2, T=8192, H=16, D=64, HD=1024, DM=1024.

#define B_SZ 2
#define T_LEN 8192
#define H_N 16
#define D_N 64
#define HD 1024
#define DM 1024

#define NCH 128                 // chunks per chain
#define CH (T_LEN / NCH)        // 64 steps per chunk

typedef unsigned short u16;
typedef __attribute__((ext_vector_type(4))) unsigned short u16x4;
typedef __attribute__((ext_vector_type(8))) short s16x8;   // 8 bf16 in 4 VGPR
typedef __attribute__((ext_vector_type(4))) float f32x4;

__device__ __forceinline__ u16 f2bf(float f) {
    union { float f; unsigned u; } v; v.f = f;
    unsigned r = v.u + 0x7fffu + ((v.u >> 16) & 1u);   // RNE
    return (u16)(r >> 16);
}
__device__ __forceinline__ float bf2f(u16 h) {
    union { unsigned u; float f; } v; v.u = ((unsigned)h) << 16;
    return v.f;
}

// ---------------- conversion kernels ----------------
__global__ __launch_bounds__(256) void conv_x_split(
    const float* __restrict__ x, u16* __restrict__ xs)
{
    size_t i = ((size_t)blockIdx.x * 256 + threadIdx.x) * 4;
    float4 v = *reinterpret_cast<const float4*>(&x[i]);
    int row = (int)(i >> 10);
    int col = (int)(i & 1023);
    float f[4] = {v.x, v.y, v.z, v.w};
    u16x4 hi, lo;
#pragma unroll
    for (int j = 0; j < 4; ++j) {
        u16 h = f2bf(f[j]);
        hi[j] = h;
        lo[j] = f2bf(f[j] - bf2f(h));
    }
    *reinterpret_cast<u16x4*>(&xs[(size_t)row * 2048 + col]) = hi;
    *reinterpret_cast<u16x4*>(&xs[(size_t)row * 2048 + 1024 + col]) = lo;
}

// Wk3 = [10Wk_hi | 10Wk_hi | 10Wk_lo]  (pairs with A cols [hi | lo | hi-wrap])
__global__ __launch_bounds__(256) void conv_wk(
    const float* __restrict__ Wk, u16* __restrict__ Wk3)
{
    size_t i = ((size_t)blockIdx.x * 256 + threadIdx.x) * 4;
    float4 v = *reinterpret_cast<const float4*>(&Wk[i]);
    int row = (int)(i >> 10);
    int col = (int)(i & 1023);
    float f[4] = {10.f * v.x, 10.f * v.y, 10.f * v.z, 10.f * v.w};
    u16x4 hi, lo;
#pragma unroll
    for (int j = 0; j < 4; ++j) {
        u16 h = f2bf(f[j]);
        hi[j] = h;
        lo[j] = f2bf(f[j] - bf2f(h));
    }
    *reinterpret_cast<u16x4*>(&Wk3[(size_t)row * 3072 + col]) = hi;
    *reinterpret_cast<u16x4*>(&Wk3[(size_t)row * 3072 + 1024 + col]) = hi;
    *reinterpret_cast<u16x4*>(&Wk3[(size_t)row * 3072 + 2048 + col]) = lo;
}

__global__ __launch_bounds__(256) void conv_w(
    const float* __restrict__ W, u16* __restrict__ Wb)
{
    size_t i = ((size_t)blockIdx.x * 256 + threadIdx.x) * 4;
    float4 v = *reinterpret_cast<const float4*>(&W[i]);
    float f[4] = {v.x, v.y, v.z, v.w};
    u16x4 hi;
#pragma unroll
    for (int j = 0; j < 4; ++j) hi[j] = f2bf(f[j]);
    *reinterpret_cast<u16x4*>(&Wb[i]) = hi;
}

// ---------------- 256x256 8-phase bf16 MFMA GEMM ----------------
// C[m,n] = sum_k A[m, wrap(k)] * W[n, k]. 512 threads = 8 waves (2M x 4N),
// per-wave 128x64 output = 8x4 frags of 16x16. BK=64, double-buffered LDS
// (128 KiB): buf b at b*65536: A[256][64] then B[256][64], bf16,
// XOR-swizzled: byte_in_row ^= (row&7)<<4.
#define GBK 64

#define BAR()    asm volatile("s_barrier" ::: "memory")
#define VMCNT4() asm volatile("s_waitcnt vmcnt(4)" ::: "memory")
#define VMCNT0() asm volatile("s_waitcnt vmcnt(0)" ::: "memory")
#define LGKM0_SB() do { asm volatile("s_waitcnt lgkmcnt(0)" ::: "memory"); \
                        __builtin_amdgcn_sched_barrier(0); } while (0)

template <int IMM>
__device__ __forceinline__ s16x8 dsr(unsigned base) {
    s16x8 r;
    asm volatile("ds_read_b128 %0, %1 offset:%2"
                 : "=v"(r) : "v"(base), "n"(IMM));
    return r;
}

__device__ __forceinline__ unsigned lds_addr(const void* p) {
    return (unsigned)(uintptr_t)(const __attribute__((address_space(3))) void*)p;
}

#define MFMA_Q(mh, nh)                                               \
  {                                                                  \
    __builtin_amdgcn_s_setprio(1);                                   \
    _Pragma("unroll")                                                \
    for (int ks_ = 0; ks_ < 2; ++ks_)                                \
      _Pragma("unroll")                                              \
      for (int m_ = 0; m_ < 4; ++m_)                                 \
        _Pragma("unroll")                                            \
        for (int n_ = 0; n_ < 2; ++n_)                               \
          acc[(mh)*4 + m_][(nh)*2 + n_] =                            \
            __builtin_amdgcn_mfma_f32_16x16x32_bf16(                 \
              aR[m_][ks_], bR[(nh)*2 + n_][ks_],                     \
              acc[(mh)*4 + m_][(nh)*2 + n_], 0, 0, 0);               \
    __builtin_amdgcn_s_setprio(0);                                   \
  }

// A rows (8 of wave tile, offset ofs = 0 for rows 0-63, 8192 for rows 64-127)
#define RD_A(ph, ofs)                                                          \
  aR[0][0]=dsr<(ofs)+0>(bA[ph][0]);    aR[1][0]=dsr<(ofs)+2048>(bA[ph][0]);    \
  aR[2][0]=dsr<(ofs)+4096>(bA[ph][0]); aR[3][0]=dsr<(ofs)+6144>(bA[ph][0]);    \
  aR[0][1]=dsr<(ofs)+0>(bA[ph][1]);    aR[1][1]=dsr<(ofs)+2048>(bA[ph][1]);    \
  aR[2][1]=dsr<(ofs)+4096>(bA[ph][1]); aR[3][1]=dsr<(ofs)+6144>(bA[ph][1]);
#define RD_B01(ph)                                                             \
  bR[0][0]=dsr<0>(bB[ph][0]);    bR[1][0]=dsr<2048>(bB[ph][0]);                \
  bR[0][1]=dsr<0>(bB[ph][1]);    bR[1][1]=dsr<2048>(bB[ph][1]);
#define RD_B23(ph)                                                             \
  bR[2][0]=dsr<4096>(bB[ph][0]); bR[3][0]=dsr<6144>(bB[ph][0]);                \
  bR[2][1]=dsr<4096>(bB[ph][1]); bR[3][1]=dsr<6144>(bB[ph][1]);

// One K-tile (4 phases). ph = compile-time 0/1 selects the LDS buffer.
#define PHASE_GROUP(ph)                                              \
  {                                                                  \
    RD_A(ph, 0); RD_B01(ph);                                         \
    if ((ph) == 0)    STAGE_A(2*t+1, 1, 0);                          \
    else if (gm)      STAGE_A(2*t+2, 0, 0);                          \
    BAR(); LGKM0_SB();                                               \
    MFMA_Q(0, 0);                                                    \
    BAR();                                                           \
    RD_B23(ph);                                                      \
    if ((ph) == 0)    STAGE_A(2*t+1, 1, 1);                          \
    else if (gm)      STAGE_A(2*t+2, 0, 1);                          \
    BAR(); LGKM0_SB();                                               \
    MFMA_Q(0, 1);                                                    \
    BAR();                                                           \
    RD_A(ph, 8192);                                                  \
    if (gm) STAGE_B(2*t+2+(ph), (ph), 0);                            \
    BAR(); LGKM0_SB();                                               \
    MFMA_Q(1, 0);                                                    \
    BAR();                                                           \
    if (gm) { STAGE_B(2*t+2+(ph), (ph), 1); VMCNT4(); }              \
    else    { VMCNT0(); }                                            \
    BAR();                                                           \
    MFMA_Q(1, 1);                                                    \
    BAR();                                                           \
  }

// Stage one half-tile (128 rows x 64 cols bf16 = 16 KB) via global_load_lds.
// LDS dest linear (wave-uniform base + lane*16); global src pre-inverse-swizzled.
__device__ __forceinline__ void stage_half(
    const u16* __restrict__ g, int ld, int rowbase, int kbase,
    char* ldshalf, int wid, int lane)
{
#pragma unroll
    for (int s = 0; s < 2; ++s) {
        const int slot = s * 512 + wid * 64 + lane;
        const int r = slot >> 3;
        const int cb = ((slot & 7) << 4) ^ ((r & 7) << 4);
        const u16* gp = g + (size_t)(rowbase + r) * ld + kbase + (cb >> 1);
        __builtin_amdgcn_global_load_lds(
            (const __attribute__((address_space(1))) void*)gp,
            (__attribute__((address_space(3))) void*)(ldshalf + s * 8192 + wid * 1024),
            16, 0, 0);
    }
}

__global__ __launch_bounds__(512, 2) void gemm_mfma256(
    const u16* __restrict__ A, int lda, const u16* __restrict__ W, int ldw,
    void* __restrict__ Cv, int ldc, int K, int kwrapA, int mode)
{
    __shared__ __align__(16) char lds[131072];

    const int tid  = threadIdx.x;
    const int lane = tid & 63;
    const int wid  = tid >> 6;      // 0..7
    const int wm   = wid >> 2;      // 0..1
    const int wn   = wid & 3;       // 0..3
    const int l15  = lane & 15;
    const int hib  = (lane >> 4) << 4;   // byte offset within k-slot row chunk

    // XCD-aware block order, specialized to grid (4, 64) = 256 blocks:
    // xcd = flat&7; within-XCD 2-wide column-major so a B-tile pair stays
    // L2-hot across 8 row-blocks (B panel = 6.3 MB > 4 MB L2 otherwise).
    const int flat = blockIdx.y * gridDim.x + blockIdx.x;
    const int xcd  = flat & 7;
    const int c    = flat >> 3;                    // 0..31
    const int bx   = ((c >> 4) << 1) | (c & 1);    // 0..3
    const int byl  = (c >> 1) & 7;                 // 0..7
    const int m0   = (xcd * 8 + byl) * 256;
    const int n0   = bx * 256;

    const int NK2 = K / (2 * GBK);

    f32x4 acc[8][4] = {};
    s16x8 aR[4][2], bR[4][2];

    // per-lane LDS base addresses (XOR-swizzle folded in; offsets via imm)
    const int Xl = (l15 & 7) << 4;
    unsigned bA[2][2], bB[2][2];
#pragma unroll
    for (int p2 = 0; p2 < 2; ++p2)
#pragma unroll
        for (int ks = 0; ks < 2; ++ks) {
            bA[p2][ks] = lds_addr(lds) + p2 * 65536 +
                         (wm * 128 + l15) * 128 + ((ks * 64 + hib) ^ Xl);
            bB[p2][ks] = lds_addr(lds) + p2 * 65536 + 32768 +
                         (wn * 64 + l15) * 128 + ((ks * 64 + hib) ^ Xl);
        }

    auto STAGE_A = [&](int kt, int buf, int h) {
        const int kb = kt * GBK;
        const int ka = (kb < kwrapA) ? kb : kb - kwrapA;
        stage_half(A, lda, m0 + h * 128, ka,
                   (char*)lds + buf * 65536 + h * 16384, wid, lane);
    };
    auto STAGE_B = [&](int kt, int buf, int h) {
        stage_half(W, ldw, n0 + h * 128, kt * GBK,
                   (char*)lds + buf * 65536 + 32768 + h * 16384, wid, lane);
    };

    // prologue: ktile0 -> buf0 (B0,B1,A0,A1); ktile1 -> buf1 (B0,B1)
    STAGE_B(0, 0, 0); STAGE_B(0, 0, 1);
    STAGE_A(0, 0, 0); STAGE_A(0, 0, 1);
    STAGE_B(1, 1, 0); STAGE_B(1, 1, 1);
    VMCNT4();         // drain ktile0's 4 half-tiles; ktile1.B stays in flight
    BAR();

    for (int t = 0; t < NK2; ++t) {
        const bool gm = (t < NK2 - 1);
        PHASE_GROUP(0)
        PHASE_GROUP(1)
    }

    // epilogue: C/D layout col=lane&15, row=(lane>>4)*4+r per 16x16 frag
    float* Cf = (float*)Cv;
    u16*   Ch = (u16*)Cv;
#pragma unroll
    for (int m = 0; m < 8; ++m) {
#pragma unroll
        for (int n = 0; n < 4; ++n) {
            const int r0  = m0 + wm * 128 + m * 16 + ((lane >> 4) << 2);
            const int col = n0 + wn * 64 + n * 16 + l15;
#pragma unroll
            for (int r = 0; r < 4; ++r) {
                const size_t off = (size_t)(r0 + r) * ldc + col;
                const float val = acc[m][n][r];
                if (mode == 0) Cf[off] = val;
                else           Ch[off] = f2bf(val);
            }
        }
    }
}

// ---------------- scan ----------------
__device__ __forceinline__ void rotor_sincos(int t, double fd, float* sr, float* cr)
{
    const double twopi = 6.283185307179586;
    const double inv2pi = 0.15915494309189535;
    double ang = (double)t * fd;
    double n = rint(ang * inv2pi);
    float red = (float)(ang - n * twopi);
    __sincosf(red, sr, cr);
}

__global__ __launch_bounds__(256) void scan_pass1(
    const u16* __restrict__ vArr, const float* __restrict__ phase,
    float* __restrict__ cs)
{
    int gw = (blockIdx.x * 256 + threadIdx.x) >> 6;
    int d = threadIdx.x & 63;
    int c = gw & (NCH - 1);
    int h = (gw >> 7) & (H_N - 1);
    int b = gw >> 11;

    double fd = 6.283185307179586 * ((double)(h + 1) / 16.0)
              * pow(10000.0, -(double)d / 64.0);

    int t0 = c * CH;
    size_t base = ((size_t)b * T_LEN + t0) * HD + (size_t)h * D_N + d;

    float cr, sr;
    rotor_sincos(t0, fd, &sr, &cr);
    float cf, sf;
    sincosf((float)fd, &sf, &cf);

    float cp = 0.f, spv = 0.f;
    if (t0 > 0) {
        float thp = phase[base - HD];
        __sincosf(thp, &spv, &cp);
    }

    float sp_re = 0.f, sp_im = 0.f, sa_re = 0.f, sa_im = 0.f;
    for (int i = 0; i < CH; ++i) {
        size_t idx = base + (size_t)i * HD;
        float v = bf2f(vArr[idx]);
        float th = phase[idx];
        sp_re = fmaf(v, cr, sp_re);
        sp_im = fmaf(v, sr, sp_im);
        sa_re = fmaf(v, cp, sa_re);
        sa_im = fmaf(-v, spv, sa_im);
        __sincosf(th, &spv, &cp);
        float nc = fmaf(cr, cf, -sr * sf);
        float ns = fmaf(sr, cf,  cr * sf);
        cr = nc; sr = ns;
    }

    const size_t NT = (size_t)B_SZ * H_N * NCH * D_N;
    size_t ci = (size_t)gw * D_N + d;
    cs[ci] = sp_re;
    cs[NT + ci] = sp_im;
    cs[2 * NT + ci] = sa_re;
    cs[3 * NT + ci] = sa_im;
}

__global__ void scan_pass2(float* __restrict__ cs)
{
    int tid = blockIdx.x * blockDim.x + threadIdx.x;
    if (tid >= B_SZ * H_N * D_N) return;
    int d = tid & 63;
    int bh = tid >> 6;
    size_t base = (size_t)bh * NCH * D_N + d;
    const size_t NT = (size_t)B_SZ * H_N * NCH * D_N;
    float r0 = 0.f, r1 = 0.f, r2 = 0.f, r3 = 0.f;
    for (int c = 0; c < NCH; ++c) {
        size_t i = base + (size_t)c * D_N;
        float a = cs[i], b2 = cs[NT + i], c2 = cs[2 * NT + i], d2 = cs[3 * NT + i];
        cs[i] = r0; cs[NT + i] = r1; cs[2 * NT + i] = r2; cs[3 * NT + i] = r3;
        r0 += a; r1 += b2; r2 += c2; r3 += d2;
    }
}

__global__ __launch_bounds__(256) void scan_pass3(
    const u16* __restrict__ vArr, const float* __restrict__ phase,
    const float* __restrict__ cs, const float* __restrict__ gate,
    u16* __restrict__ y)
{
    int gw = (blockIdx.x * 256 + threadIdx.x) >> 6;
    int d = threadIdx.x & 63;
    int c = gw & (NCH - 1);
    int h = (gw >> 7) & (H_N - 1);
    int b = gw >> 11;

    double fd = 6.283185307179586 * ((double)(h + 1) / 16.0)
              * pow(10000.0, -(double)d / 64.0);
    float g0 = gate[h * 2 + 0];
    float g1 = gate[h * 2 + 1];

    int t0 = c * CH;
    size_t base = ((size_t)b * T_LEN + t0) * HD + (size_t)h * D_N + d;

    const size_t NT = (size_t)B_SZ * H_N * NCH * D_N;
    size_t ci = (size_t)gw * D_N + d;
    float ap_re = cs[ci];
    float ap_im = cs[NT + ci];
    float aa_re = cs[2 * NT + ci];
    float aa_im = cs[3 * NT + ci];

    float cr, sr;
    rotor_sincos(t0, fd, &sr, &cr);
    float cf, sf;
    sincosf((float)fd, &sf, &cf);

    float cp = 0.f, spv = 0.f;
    if (t0 > 0) {
        float thp = phase[base - HD];
        __sincosf(thp, &spv, &cp);
    }

    for (int i = 0; i < CH; ++i) {
        int t = t0 + i;
        size_t idx = base + (size_t)i * HD;
        float v = bf2f(vArr[idx]);
        float th = phase[idx];
        ap_re = fmaf(v, cr, ap_re);
        ap_im = fmaf(v, sr, ap_im);
        aa_re = fmaf(v, cp, aa_re);
        aa_im = fmaf(-v, spv, aa_im);
        float op = fmaf(ap_re, cr, ap_im * sr);
        float ck, sk;
        __sincosf(th, &sk, &ck);
        float oa = fmaf(aa_re, ck, -aa_im * sk);
        float sc = rsqrtf((float)(t + 1));
        y[idx] = f2bf((g0 * op + g1 * oa) * sc);
        cp = ck; spv = sk;
        float nc = fmaf(cr, cf, -sr * sf);
        float ns = fmaf(sr, cf,  cr * sf);
        cr = nc; sr = ns;
    }
}

// ---------------- launch ----------------
extern "C" void kernel_launch(void* const* d_in, const int* in_sizes, int n_in,
                              void* d_out, int out_size, void* d_ws, size_t ws_size,
                              hipStream_t stream)
{
    const float* x    = (const float*)d_in[0];
    const float* Wk   = (const float*)d_in[1];
    const float* Wv   = (const float*)d_in[2];
    const float* Wo   = (const float*)d_in[3];
    const float* gate = (const float*)d_in[4];
    float* out = (float*)d_out;

    // phase lives in d_out (dead before the final GEMM overwrites it).
    float* phase = (float*)d_out;

    // ws layout (MiB offsets):
    //   0   : xs   [16384][2048] bf16 (hi|lo) = 64   -- yb aliases it later
    //   64  : vb   [16384][1024] bf16        = 32
    //   96  : cs   4 * 2*16*128*64 f32       = 4
    //   100 : Wk3  [1024][3072] bf16         = 6
    //   106 : Wvb                              2
    //   108 : Wob                              2     total 110 MiB
    char* wsb = (char*)d_ws;
    u16*   xs  = (u16*)wsb;
    u16*   yb  = (u16*)wsb;                       // alias: xs dead after v-GEMM
    u16*   vb  = (u16*)(wsb + (64ull << 20));
    float* cs  = (float*)(wsb + (96ull << 20));
    u16*   Wk3 = (u16*)(wsb + (100ull << 20));
    u16*   Wvb = (u16*)(wsb + (106ull << 20));
    u16*   Wob = (u16*)(wsb + (108ull << 20));

    hipLaunchKernelGGL(conv_x_split, dim3(16384), dim3(256), 0, stream, x, xs);
    hipLaunchKernelGGL(conv_wk, dim3(1024), dim3(256), 0, stream, Wk, Wk3);
    hipLaunchKernelGGL(conv_w,  dim3(1024), dim3(256), 0, stream, Wv, Wvb);
    hipLaunchKernelGGL(conv_w,  dim3(1024), dim3(256), 0, stream, Wo, Wob);

    const dim3 gblk(512);
    const dim3 ggrid(HD / 256, (B_SZ * T_LEN) / 256);   // (4, 64) = 256 blocks

    // phase = xhi@10Wkhi^T + xlo@10Wkhi^T + xhi@10Wklo^T  (K=3072, A wraps at 2048)
    hipLaunchKernelGGL(gemm_mfma256, ggrid, gblk, 0, stream,
                       xs, 2048, Wk3, 3072, (void*)phase, HD, 3072, 2048, 0);
    // vb = bf16(xhi@Wv^T)
    hipLaunchKernelGGL(gemm_mfma256, ggrid, gblk, 0, stream,
                       xs, 2048, Wvb, 1024, (void*)vb, HD, 1024, 1 << 30, 2);

    const int waves = B_SZ * H_N * NCH;   // 4096
    hipLaunchKernelGGL(scan_pass1, dim3(waves / 4), dim3(256), 0, stream, vb, phase, cs);
    hipLaunchKernelGGL(scan_pass2, dim3(8), dim3(256), 0, stream, cs);
    hipLaunchKernelGGL(scan_pass3, dim3(waves / 4), dim3(256), 0, stream, vb, phase, cs, gate, yb);

    // out = yb@Wo^T  (overwrites phase in d_out)
    hipLaunchKernelGGL(gemm_mfma256, ggrid, gblk, 0, stream,
                       yb, 1024, Wob, 1024, (void*)out, HD, 1024, 1 << 30, 0);
}

// Round 6
// 247.882 us; speedup vs baseline: 5.2069x; 1.0003x over previous
//
#include <hip/hip_runtime.h>
#include <math.h>

// HoloAttentionV2 on MI355X (gfx950).
// 256x256 bf16 MFMA GEMM, 4-phase/2-K-tile schedule (32-MFMA clusters),
// T1 XCD swizzle + T2 LDS XOR swizzle + counted vmcnt + setprio.
// Split-bf16 K=3072 phase GEMM via A-column wrap; 3-pass chunked complex scan.
// Shapes: B=2, T=8192, H=16, D=64, HD=1024, DM=1024.

#define B_SZ 2
#define T_LEN 8192
#define H_N 16
#define D_N 64
#define HD 1024
#define DM 1024

#define NCH 128                 // chunks per chain
#define CH (T_LEN / NCH)        // 64 steps per chunk

typedef unsigned short u16;
typedef __attribute__((ext_vector_type(4))) unsigned short u16x4;
typedef __attribute__((ext_vector_type(8))) short s16x8;   // 8 bf16 in 4 VGPR
typedef __attribute__((ext_vector_type(4))) float f32x4;

__device__ __forceinline__ u16 f2bf(float f) {
    union { float f; unsigned u; } v; v.f = f;
    unsigned r = v.u + 0x7fffu + ((v.u >> 16) & 1u);   // RNE
    return (u16)(r >> 16);
}
__device__ __forceinline__ float bf2f(u16 h) {
    union { unsigned u; float f; } v; v.u = ((unsigned)h) << 16;
    return v.f;
}

// ---------------- conversion kernels ----------------
__global__ __launch_bounds__(256) void conv_x_split(
    const float* __restrict__ x, u16* __restrict__ xs)
{
    size_t i = ((size_t)blockIdx.x * 256 + threadIdx.x) * 4;
    float4 v = *reinterpret_cast<const float4*>(&x[i]);
    int row = (int)(i >> 10);
    int col = (int)(i & 1023);
    float f[4] = {v.x, v.y, v.z, v.w};
    u16x4 hi, lo;
#pragma unroll
    for (int j = 0; j < 4; ++j) {
        u16 h = f2bf(f[j]);
        hi[j] = h;
        lo[j] = f2bf(f[j] - bf2f(h));
    }
    *reinterpret_cast<u16x4*>(&xs[(size_t)row * 2048 + col]) = hi;
    *reinterpret_cast<u16x4*>(&xs[(size_t)row * 2048 + 1024 + col]) = lo;
}

// Wk3 = [10Wk_hi | 10Wk_hi | 10Wk_lo]  (pairs with A cols [hi | lo | hi-wrap])
__global__ __launch_bounds__(256) void conv_wk(
    const float* __restrict__ Wk, u16* __restrict__ Wk3)
{
    size_t i = ((size_t)blockIdx.x * 256 + threadIdx.x) * 4;
    float4 v = *reinterpret_cast<const float4*>(&Wk[i]);
    int row = (int)(i >> 10);
    int col = (int)(i & 1023);
    float f[4] = {10.f * v.x, 10.f * v.y, 10.f * v.z, 10.f * v.w};
    u16x4 hi, lo;
#pragma unroll
    for (int j = 0; j < 4; ++j) {
        u16 h = f2bf(f[j]);
        hi[j] = h;
        lo[j] = f2bf(f[j] - bf2f(h));
    }
    *reinterpret_cast<u16x4*>(&Wk3[(size_t)row * 3072 + col]) = hi;
    *reinterpret_cast<u16x4*>(&Wk3[(size_t)row * 3072 + 1024 + col]) = hi;
    *reinterpret_cast<u16x4*>(&Wk3[(size_t)row * 3072 + 2048 + col]) = lo;
}

__global__ __launch_bounds__(256) void conv_w(
    const float* __restrict__ W, u16* __restrict__ Wb)
{
    size_t i = ((size_t)blockIdx.x * 256 + threadIdx.x) * 4;
    float4 v = *reinterpret_cast<const float4*>(&W[i]);
    float f[4] = {v.x, v.y, v.z, v.w};
    u16x4 hi;
#pragma unroll
    for (int j = 0; j < 4; ++j) hi[j] = f2bf(f[j]);
    *reinterpret_cast<u16x4*>(&Wb[i]) = hi;
}

// ---------------- 256x256 4-phase bf16 MFMA GEMM ----------------
// C[m,n] = sum_k A[m, wrap(k)] * W[n, k]. 512 threads = 8 waves (2M x 4N),
// per-wave 128x64 output = 8x4 frags of 16x16. BK=64, double-buffered LDS
// (128 KiB): buf b at b*65536: A[256][64] then B[256][64], bf16,
// XOR-swizzled: byte_in_row ^= (row&7)<<4.
#define GBK 64

#define BAR()     asm volatile("s_barrier" ::: "memory")
#define VMCNT4()  asm volatile("s_waitcnt vmcnt(4)" ::: "memory")
#define VMCNT0()  asm volatile("s_waitcnt vmcnt(0)" ::: "memory")
#define LGKM8PRE() asm volatile("s_waitcnt lgkmcnt(8)" ::: "memory")
#define LGKM0_SB() do { asm volatile("s_waitcnt lgkmcnt(0)" ::: "memory"); \
                        __builtin_amdgcn_sched_barrier(0); } while (0)

template <int IMM>
__device__ __forceinline__ s16x8 dsr(unsigned base) {
    s16x8 r;
    asm volatile("ds_read_b128 %0, %1 offset:%2"
                 : "=v"(r) : "v"(base), "n"(IMM));
    return r;
}

__device__ __forceinline__ unsigned lds_addr(const void* p) {
    return (unsigned)(uintptr_t)(const __attribute__((address_space(3))) void*)p;
}

// 16 MFMA (no setprio inside; caller wraps clusters)
#define MFMA_Q(mh, nh)                                               \
  {                                                                  \
    _Pragma("unroll")                                                \
    for (int ks_ = 0; ks_ < 2; ++ks_)                                \
      _Pragma("unroll")                                              \
      for (int m_ = 0; m_ < 4; ++m_)                                 \
        _Pragma("unroll")                                            \
        for (int n_ = 0; n_ < 2; ++n_)                               \
          acc[(mh)*4 + m_][(nh)*2 + n_] =                            \
            __builtin_amdgcn_mfma_f32_16x16x32_bf16(                 \
              aR[m_][ks_], bR[(nh)*2 + n_][ks_],                     \
              acc[(mh)*4 + m_][(nh)*2 + n_], 0, 0, 0);               \
  }

// A rows (8 of wave tile, offset ofs = 0 for rows 0-63, 8192 for rows 64-127)
#define RD_A(ph, ofs)                                                          \
  aR[0][0]=dsr<(ofs)+0>(bA[ph][0]);    aR[1][0]=dsr<(ofs)+2048>(bA[ph][0]);    \
  aR[2][0]=dsr<(ofs)+4096>(bA[ph][0]); aR[3][0]=dsr<(ofs)+6144>(bA[ph][0]);    \
  aR[0][1]=dsr<(ofs)+0>(bA[ph][1]);    aR[1][1]=dsr<(ofs)+2048>(bA[ph][1]);    \
  aR[2][1]=dsr<(ofs)+4096>(bA[ph][1]); aR[3][1]=dsr<(ofs)+6144>(bA[ph][1]);
#define RD_B01(ph)                                                             \
  bR[0][0]=dsr<0>(bB[ph][0]);    bR[1][0]=dsr<2048>(bB[ph][0]);                \
  bR[0][1]=dsr<0>(bB[ph][1]);    bR[1][1]=dsr<2048>(bB[ph][1]);
#define RD_B23(ph)                                                             \
  bR[2][0]=dsr<4096>(bB[ph][0]); bR[3][0]=dsr<6144>(bB[ph][0]);                \
  bR[2][1]=dsr<4096>(bB[ph][1]); bR[3][1]=dsr<6144>(bB[ph][1]);

// One K-tile, 2 phases (P1: top-half A rows, P2: bottom-half). ph = buffer.
// Race audit: B-stage (P2 -> buf[ph].B) is after P1's lgkm0 drained this
// group's B reads; A-stage (P1 -> buf[ph^1].A) is after prev group's P2 lgkm0
// drained its A-bottom reads. vmcnt(4) at P2 drains next buffer's A+B, keeps
// the following B half-pair in flight (carry-in 4, matches prologue).
#define PHASE_GROUP(ph)                                              \
  {                                                                  \
    RD_A(ph, 0); RD_B01(ph); RD_B23(ph);                             \
    LGKM8PRE();                                                      \
    if ((ph) == 0)    { STAGE_A(2*t+1, 1, 0); STAGE_A(2*t+1, 1, 1); }\
    else if (gm)      { STAGE_A(2*t+2, 0, 0); STAGE_A(2*t+2, 0, 1); }\
    BAR(); LGKM0_SB();                                               \
    __builtin_amdgcn_s_setprio(1);                                   \
    MFMA_Q(0, 0); MFMA_Q(0, 1);                                      \
    __builtin_amdgcn_s_setprio(0);                                   \
    BAR();                                                           \
    RD_A(ph, 8192);                                                  \
    if (gm) { STAGE_B(2*t+2+(ph), (ph), 0);                          \
              STAGE_B(2*t+2+(ph), (ph), 1); VMCNT4(); }              \
    else    { VMCNT0(); }                                            \
    BAR(); LGKM0_SB();                                               \
    __builtin_amdgcn_s_setprio(1);                                   \
    MFMA_Q(1, 0); MFMA_Q(1, 1);                                      \
    __builtin_amdgcn_s_setprio(0);                                   \
    BAR();                                                           \
  }

// Stage one half-tile (128 rows x 64 cols bf16 = 16 KB) via global_load_lds.
// LDS dest linear (wave-uniform base + lane*16); global src pre-inverse-swizzled.
__device__ __forceinline__ void stage_half(
    const u16* __restrict__ g, int ld, int rowbase, int kbase,
    char* ldshalf, int wid, int lane)
{
#pragma unroll
    for (int s = 0; s < 2; ++s) {
        const int slot = s * 512 + wid * 64 + lane;
        const int r = slot >> 3;
        const int cb = ((slot & 7) << 4) ^ ((r & 7) << 4);
        const u16* gp = g + (size_t)(rowbase + r) * ld + kbase + (cb >> 1);
        __builtin_amdgcn_global_load_lds(
            (const __attribute__((address_space(1))) void*)gp,
            (__attribute__((address_space(3))) void*)(ldshalf + s * 8192 + wid * 1024),
            16, 0, 0);
    }
}

__global__ __launch_bounds__(512, 2) void gemm_mfma256(
    const u16* __restrict__ A, int lda, const u16* __restrict__ W, int ldw,
    void* __restrict__ Cv, int ldc, int K, int kwrapA, int mode)
{
    __shared__ __align__(16) char lds[131072];

    const int tid  = threadIdx.x;
    const int lane = tid & 63;
    const int wid  = tid >> 6;      // 0..7
    const int wm   = wid >> 2;      // 0..1
    const int wn   = wid & 3;       // 0..3
    const int l15  = lane & 15;
    const int hib  = (lane >> 4) << 4;   // byte offset within k-slot row chunk

    // XCD-aware block order, specialized to grid (4, 64) = 256 blocks:
    // xcd = flat&7; within-XCD 2-wide column-major so a B-tile pair stays
    // L2-hot across 8 row-blocks.
    const int flat = blockIdx.y * gridDim.x + blockIdx.x;
    const int xcd  = flat & 7;
    const int c    = flat >> 3;                    // 0..31
    const int bx   = ((c >> 4) << 1) | (c & 1);    // 0..3
    const int byl  = (c >> 1) & 7;                 // 0..7
    const int m0   = (xcd * 8 + byl) * 256;
    const int n0   = bx * 256;

    const int NK2 = K / (2 * GBK);

    f32x4 acc[8][4] = {};
    s16x8 aR[4][2], bR[4][2];

    // per-lane LDS base addresses (XOR-swizzle folded in; offsets via imm)
    const int Xl = (l15 & 7) << 4;
    unsigned bA[2][2], bB[2][2];
#pragma unroll
    for (int p2 = 0; p2 < 2; ++p2)
#pragma unroll
        for (int ks = 0; ks < 2; ++ks) {
            bA[p2][ks] = lds_addr(lds) + p2 * 65536 +
                         (wm * 128 + l15) * 128 + ((ks * 64 + hib) ^ Xl);
            bB[p2][ks] = lds_addr(lds) + p2 * 65536 + 32768 +
                         (wn * 64 + l15) * 128 + ((ks * 64 + hib) ^ Xl);
        }

    auto STAGE_A = [&](int kt, int buf, int h) {
        const int kb = kt * GBK;
        const int ka = (kb < kwrapA) ? kb : kb - kwrapA;
        stage_half(A, lda, m0 + h * 128, ka,
                   (char*)lds + buf * 65536 + h * 16384, wid, lane);
    };
    auto STAGE_B = [&](int kt, int buf, int h) {
        stage_half(W, ldw, n0 + h * 128, kt * GBK,
                   (char*)lds + buf * 65536 + 32768 + h * 16384, wid, lane);
    };

    // prologue: ktile0 -> buf0 (B0,B1,A0,A1); ktile1 -> buf1 (B0,B1)
    STAGE_B(0, 0, 0); STAGE_B(0, 0, 1);
    STAGE_A(0, 0, 0); STAGE_A(0, 0, 1);
    STAGE_B(1, 1, 0); STAGE_B(1, 1, 1);
    VMCNT4();         // drain ktile0's 4 half-tiles; ktile1.B stays in flight
    BAR();

    for (int t = 0; t < NK2; ++t) {
        const bool gm = (t < NK2 - 1);
        PHASE_GROUP(0)
        PHASE_GROUP(1)
    }

    // epilogue: C/D layout col=lane&15, row=(lane>>4)*4+r per 16x16 frag
    float* Cf = (float*)Cv;
    u16*   Ch = (u16*)Cv;
#pragma unroll
    for (int m = 0; m < 8; ++m) {
#pragma unroll
        for (int n = 0; n < 4; ++n) {
            const int r0  = m0 + wm * 128 + m * 16 + ((lane >> 4) << 2);
            const int col = n0 + wn * 64 + n * 16 + l15;
#pragma unroll
            for (int r = 0; r < 4; ++r) {
                const size_t off = (size_t)(r0 + r) * ldc + col;
                const float val = acc[m][n][r];
                if (mode == 0) Cf[off] = val;
                else           Ch[off] = f2bf(val);
            }
        }
    }
}

// ---------------- scan ----------------
__device__ __forceinline__ void rotor_sincos(int t, double fd, float* sr, float* cr)
{
    const double twopi = 6.283185307179586;
    const double inv2pi = 0.15915494309189535;
    double ang = (double)t * fd;
    double n = rint(ang * inv2pi);
    float red = (float)(ang - n * twopi);
    __sincosf(red, sr, cr);
}

__global__ __launch_bounds__(256) void scan_pass1(
    const u16* __restrict__ vArr, const float* __restrict__ phase,
    float* __restrict__ cs)
{
    int gw = (blockIdx.x * 256 + threadIdx.x) >> 6;
    int d = threadIdx.x & 63;
    int c = gw & (NCH - 1);
    int h = (gw >> 7) & (H_N - 1);
    int b = gw >> 11;

    double fd = 6.283185307179586 * ((double)(h + 1) / 16.0)
              * pow(10000.0, -(double)d / 64.0);

    int t0 = c * CH;
    size_t base = ((size_t)b * T_LEN + t0) * HD + (size_t)h * D_N + d;

    float cr, sr;
    rotor_sincos(t0, fd, &sr, &cr);
    float cf, sf;
    sincosf((float)fd, &sf, &cf);

    float cp = 0.f, spv = 0.f;
    if (t0 > 0) {
        float thp = phase[base - HD];
        __sincosf(thp, &spv, &cp);
    }

    float sp_re = 0.f, sp_im = 0.f, sa_re = 0.f, sa_im = 0.f;
    for (int i = 0; i < CH; ++i) {
        size_t idx = base + (size_t)i * HD;
        float v = bf2f(vArr[idx]);
        float th = phase[idx];
        sp_re = fmaf(v, cr, sp_re);
        sp_im = fmaf(v, sr, sp_im);
        sa_re = fmaf(v, cp, sa_re);
        sa_im = fmaf(-v, spv, sa_im);
        __sincosf(th, &spv, &cp);
        float nc = fmaf(cr, cf, -sr * sf);
        float ns = fmaf(sr, cf,  cr * sf);
        cr = nc; sr = ns;
    }

    const size_t NT = (size_t)B_SZ * H_N * NCH * D_N;
    size_t ci = (size_t)gw * D_N + d;
    cs[ci] = sp_re;
    cs[NT + ci] = sp_im;
    cs[2 * NT + ci] = sa_re;
    cs[3 * NT + ci] = sa_im;
}

__global__ void scan_pass2(float* __restrict__ cs)
{
    int tid = blockIdx.x * blockDim.x + threadIdx.x;
    if (tid >= B_SZ * H_N * D_N) return;
    int d = tid & 63;
    int bh = tid >> 6;
    size_t base = (size_t)bh * NCH * D_N + d;
    const size_t NT = (size_t)B_SZ * H_N * NCH * D_N;
    float r0 = 0.f, r1 = 0.f, r2 = 0.f, r3 = 0.f;
    for (int c = 0; c < NCH; ++c) {
        size_t i = base + (size_t)c * D_N;
        float a = cs[i], b2 = cs[NT + i], c2 = cs[2 * NT + i], d2 = cs[3 * NT + i];
        cs[i] = r0; cs[NT + i] = r1; cs[2 * NT + i] = r2; cs[3 * NT + i] = r3;
        r0 += a; r1 += b2; r2 += c2; r3 += d2;
    }
}

__global__ __launch_bounds__(256) void scan_pass3(
    const u16* __restrict__ vArr, const float* __restrict__ phase,
    const float* __restrict__ cs, const float* __restrict__ gate,
    u16* __restrict__ y)
{
    int gw = (blockIdx.x * 256 + threadIdx.x) >> 6;
    int d = threadIdx.x & 63;
    int c = gw & (NCH - 1);
    int h = (gw >> 7) & (H_N - 1);
    int b = gw >> 11;

    double fd = 6.283185307179586 * ((double)(h + 1) / 16.0)
              * pow(10000.0, -(double)d / 64.0);
    float g0 = gate[h * 2 + 0];
    float g1 = gate[h * 2 + 1];

    int t0 = c * CH;
    size_t base = ((size_t)b * T_LEN + t0) * HD + (size_t)h * D_N + d;

    const size_t NT = (size_t)B_SZ * H_N * NCH * D_N;
    size_t ci = (size_t)gw * D_N + d;
    float ap_re = cs[ci];
    float ap_im = cs[NT + ci];
    float aa_re = cs[2 * NT + ci];
    float aa_im = cs[3 * NT + ci];

    float cr, sr;
    rotor_sincos(t0, fd, &sr, &cr);
    float cf, sf;
    sincosf((float)fd, &sf, &cf);

    float cp = 0.f, spv = 0.f;
    if (t0 > 0) {
        float thp = phase[base - HD];
        __sincosf(thp, &spv, &cp);
    }

    for (int i = 0; i < CH; ++i) {
        int t = t0 + i;
        size_t idx = base + (size_t)i * HD;
        float v = bf2f(vArr[idx]);
        float th = phase[idx];
        ap_re = fmaf(v, cr, ap_re);
        ap_im = fmaf(v, sr, ap_im);
        aa_re = fmaf(v, cp, aa_re);
        aa_im = fmaf(-v, spv, aa_im);
        float op = fmaf(ap_re, cr, ap_im * sr);
        float ck, sk;
        __sincosf(th, &sk, &ck);
        float oa = fmaf(aa_re, ck, -aa_im * sk);
        float sc = rsqrtf((float)(t + 1));
        y[idx] = f2bf((g0 * op + g1 * oa) * sc);
        cp = ck; spv = sk;
        float nc = fmaf(cr, cf, -sr * sf);
        float ns = fmaf(sr, cf,  cr * sf);
        cr = nc; sr = ns;
    }
}

// ---------------- launch ----------------
extern "C" void kernel_launch(void* const* d_in, const int* in_sizes, int n_in,
                              void* d_out, int out_size, void* d_ws, size_t ws_size,
                              hipStream_t stream)
{
    const float* x    = (const float*)d_in[0];
    const float* Wk   = (const float*)d_in[1];
    const float* Wv   = (const float*)d_in[2];
    const float* Wo   = (const float*)d_in[3];
    const float* gate = (const float*)d_in[4];
    float* out = (float*)d_out;

    // phase lives in d_out (dead before the final GEMM overwrites it).
    float* phase = (float*)d_out;

    // ws layout (MiB offsets):
    //   0   : xs   [16384][2048] bf16 (hi|lo) = 64   -- yb aliases it later
    //   64  : vb   [16384][1024] bf16        = 32
    //   96  : cs   4 * 2*16*128*64 f32       = 4
    //   100 : Wk3  [1024][3072] bf16         = 6
    //   106 : Wvb                              2
    //   108 : Wob                              2     total 110 MiB
    char* wsb = (char*)d_ws;
    u16*   xs  = (u16*)wsb;
    u16*   yb  = (u16*)wsb;                       // alias: xs dead after v-GEMM
    u16*   vb  = (u16*)(wsb + (64ull << 20));
    float* cs  = (float*)(wsb + (96ull << 20));
    u16*   Wk3 = (u16*)(wsb + (100ull << 20));
    u16*   Wvb = (u16*)(wsb + (106ull << 20));
    u16*   Wob = (u16*)(wsb + (108ull << 20));

    hipLaunchKernelGGL(conv_x_split, dim3(16384), dim3(256), 0, stream, x, xs);
    hipLaunchKernelGGL(conv_wk, dim3(1024), dim3(256), 0, stream, Wk, Wk3);
    hipLaunchKernelGGL(conv_w,  dim3(1024), dim3(256), 0, stream, Wv, Wvb);
    hipLaunchKernelGGL(conv_w,  dim3(1024), dim3(256), 0, stream, Wo, Wob);

    const dim3 gblk(512);
    const dim3 ggrid(HD / 256, (B_SZ * T_LEN) / 256);   // (4, 64) = 256 blocks

    // phase = xhi@10Wkhi^T + xlo@10Wkhi^T + xhi@10Wklo^T  (K=3072, A wraps at 2048)
    hipLaunchKernelGGL(gemm_mfma256, ggrid, gblk, 0, stream,
                       xs, 2048, Wk3, 3072, (void*)phase, HD, 3072, 2048, 0);
    // vb = bf16(xhi@Wv^T)
    hipLaunchKernelGGL(gemm_mfma256, ggrid, gblk, 0, stream,
                       xs, 2048, Wvb, 1024, (void*)vb, HD, 1024, 1 << 30, 2);

    const int waves = B_SZ * H_N * NCH;   // 4096
    hipLaunchKernelGGL(scan_pass1, dim3(waves / 4), dim3(256), 0, stream, vb, phase, cs);
    hipLaunchKernelGGL(scan_pass2, dim3(8), dim3(256), 0, stream, cs);
    hipLaunchKernelGGL(scan_pass3, dim3(waves / 4), dim3(256), 0, stream, vb, phase, cs, gate, yb);

    // out = yb@Wo^T  (overwrites phase in d_out)
    hipLaunchKernelGGL(gemm_mfma256, ggrid, gblk, 0, stream,
                       yb, 1024, Wob, 1024, (void*)out, HD, 1024, 1 << 30, 0);
}

// Round 7
// 190.715 us; speedup vs baseline: 6.7677x; 1.2998x over previous
//
#include <hip/hip_runtime.h>
#include <math.h>

// HoloAttentionV2 on MI355X (gfx950).
// fp16 MFMA GEMMs (11-bit mantissa kills the bf16 hi/lo split: phase GEMM is
// a single K=1024 pass). Merged [10Wk|Wv] GEMM (N=2048, mixed f32/fp16
// epilogue) + out GEMM. 256x256 tile, 4-phase/2-K-tile schedule, T1 XCD
// swizzle + T2 LDS XOR swizzle + counted vmcnt + setprio.
// 3-pass chunked complex scan. Shapes: B=2, T=8192, H=16, D=64, HD=DM=1024.

#define B_SZ 2
#define T_LEN 8192
#define H_N 16
#define D_N 64
#define HD 1024
#define DM 1024

#define NCH 128                 // chunks per chain
#define CH (T_LEN / NCH)        // 64 steps per chunk

typedef unsigned short u16;
typedef __attribute__((ext_vector_type(4))) unsigned short u16x4;
typedef __attribute__((ext_vector_type(8))) short s16x8;     // 16B LDS payload
typedef __attribute__((ext_vector_type(8))) _Float16 f16x8;  // MFMA operand
typedef __attribute__((ext_vector_type(4))) float f32x4;

__device__ __forceinline__ u16 f2h(float f) {
    return __builtin_bit_cast(u16, (_Float16)f);    // v_cvt_f16_f32, RNE
}
__device__ __forceinline__ float h2f(u16 h) {
    return (float)__builtin_bit_cast(_Float16, h);
}

// ---------------- conversion kernels ----------------
__global__ __launch_bounds__(256) void conv_x_h(
    const float* __restrict__ x, u16* __restrict__ xh)
{
    size_t i = ((size_t)blockIdx.x * 256 + threadIdx.x) * 4;
    float4 v = *reinterpret_cast<const float4*>(&x[i]);
    u16x4 o = { f2h(v.x), f2h(v.y), f2h(v.z), f2h(v.w) };
    *reinterpret_cast<u16x4*>(&xh[i]) = o;
}

// Wkv rows 0..1023 = 10*Wk, rows 1024..2047 = Wv  (fp16)
__global__ __launch_bounds__(256) void conv_wkv(
    const float* __restrict__ Wk, const float* __restrict__ Wv,
    u16* __restrict__ Wkv)
{
    size_t i = ((size_t)blockIdx.x * 256 + threadIdx.x) * 4;  // Wkv elem index
    int r = (int)(i >> 10);
    size_t src = (i & (1024 * 1024 - 1));
    float4 v;
    float s;
    if (r < 1024) { v = *reinterpret_cast<const float4*>(&Wk[i]); s = 10.f; }
    else          { v = *reinterpret_cast<const float4*>(&Wv[src]); s = 1.f; }
    u16x4 o = { f2h(s * v.x), f2h(s * v.y), f2h(s * v.z), f2h(s * v.w) };
    *reinterpret_cast<u16x4*>(&Wkv[i]) = o;
}

__global__ __launch_bounds__(256) void conv_w(
    const float* __restrict__ W, u16* __restrict__ Wb)
{
    size_t i = ((size_t)blockIdx.x * 256 + threadIdx.x) * 4;
    float4 v = *reinterpret_cast<const float4*>(&W[i]);
    u16x4 o = { f2h(v.x), f2h(v.y), f2h(v.z), f2h(v.w) };
    *reinterpret_cast<u16x4*>(&Wb[i]) = o;
}

// ---------------- 256x256 4-phase fp16 MFMA GEMM ----------------
// C[m,n] = sum_k A[m,k] * W[n,k]. 512 threads = 8 waves (2M x 4N),
// per-wave 128x64 output = 8x4 frags of 16x16. BK=64, double-buffered LDS
// (128 KiB): buf b at b*65536: A[256][64] then B[256][64], fp16,
// XOR-swizzled: byte_in_row ^= (row&7)<<4.
#define GBK 64

#define BAR()     asm volatile("s_barrier" ::: "memory")
#define VMCNT4()  asm volatile("s_waitcnt vmcnt(4)" ::: "memory")
#define VMCNT0()  asm volatile("s_waitcnt vmcnt(0)" ::: "memory")
#define LGKM8PRE() asm volatile("s_waitcnt lgkmcnt(8)" ::: "memory")
#define LGKM0_SB() do { asm volatile("s_waitcnt lgkmcnt(0)" ::: "memory"); \
                        __builtin_amdgcn_sched_barrier(0); } while (0)

template <int IMM>
__device__ __forceinline__ s16x8 dsr(unsigned base) {
    s16x8 r;
    asm volatile("ds_read_b128 %0, %1 offset:%2"
                 : "=v"(r) : "v"(base), "n"(IMM));
    return r;
}

__device__ __forceinline__ unsigned lds_addr(const void* p) {
    return (unsigned)(uintptr_t)(const __attribute__((address_space(3))) void*)p;
}

// 16 fp16 MFMA (caller wraps clusters with setprio)
#define MFMA_Q(mh, nh)                                               \
  {                                                                  \
    _Pragma("unroll")                                                \
    for (int ks_ = 0; ks_ < 2; ++ks_)                                \
      _Pragma("unroll")                                              \
      for (int m_ = 0; m_ < 4; ++m_)                                 \
        _Pragma("unroll")                                            \
        for (int n_ = 0; n_ < 2; ++n_)                               \
          acc[(mh)*4 + m_][(nh)*2 + n_] =                            \
            __builtin_amdgcn_mfma_f32_16x16x32_f16(                  \
              __builtin_bit_cast(f16x8, aR[m_][ks_]),                \
              __builtin_bit_cast(f16x8, bR[(nh)*2 + n_][ks_]),       \
              acc[(mh)*4 + m_][(nh)*2 + n_], 0, 0, 0);               \
  }

// A rows (8 of wave tile, offset ofs = 0 for rows 0-63, 8192 for rows 64-127)
#define RD_A(ph, ofs)                                                          \
  aR[0][0]=dsr<(ofs)+0>(bA[ph][0]);    aR[1][0]=dsr<(ofs)+2048>(bA[ph][0]);    \
  aR[2][0]=dsr<(ofs)+4096>(bA[ph][0]); aR[3][0]=dsr<(ofs)+6144>(bA[ph][0]);    \
  aR[0][1]=dsr<(ofs)+0>(bA[ph][1]);    aR[1][1]=dsr<(ofs)+2048>(bA[ph][1]);    \
  aR[2][1]=dsr<(ofs)+4096>(bA[ph][1]); aR[3][1]=dsr<(ofs)+6144>(bA[ph][1]);
#define RD_B01(ph)                                                             \
  bR[0][0]=dsr<0>(bB[ph][0]);    bR[1][0]=dsr<2048>(bB[ph][0]);                \
  bR[0][1]=dsr<0>(bB[ph][1]);    bR[1][1]=dsr<2048>(bB[ph][1]);
#define RD_B23(ph)                                                             \
  bR[2][0]=dsr<4096>(bB[ph][0]); bR[3][0]=dsr<6144>(bB[ph][0]);                \
  bR[2][1]=dsr<4096>(bB[ph][1]); bR[3][1]=dsr<6144>(bB[ph][1]);

// One K-tile, 2 phases. ph = buffer. Race audit: B-stage (P2 -> buf[ph].B)
// after P1's lgkm0 drained this group's B reads; A-stage (P1 -> buf[ph^1].A)
// after prev group's P2 lgkm0 drained its A-bottom reads. vmcnt(4) at P2
// drains next buffer's A+B, keeps following B half-pair in flight.
#define PHASE_GROUP(ph)                                              \
  {                                                                  \
    RD_A(ph, 0); RD_B01(ph); RD_B23(ph);                             \
    LGKM8PRE();                                                      \
    if ((ph) == 0)    { STAGE_A(2*t+1, 1, 0); STAGE_A(2*t+1, 1, 1); }\
    else if (gm)      { STAGE_A(2*t+2, 0, 0); STAGE_A(2*t+2, 0, 1); }\
    BAR(); LGKM0_SB();                                               \
    __builtin_amdgcn_s_setprio(1);                                   \
    MFMA_Q(0, 0); MFMA_Q(0, 1);                                      \
    __builtin_amdgcn_s_setprio(0);                                   \
    BAR();                                                           \
    RD_A(ph, 8192);                                                  \
    if (gm) { STAGE_B(2*t+2+(ph), (ph), 0);                          \
              STAGE_B(2*t+2+(ph), (ph), 1); VMCNT4(); }              \
    else    { VMCNT0(); }                                            \
    BAR(); LGKM0_SB();                                               \
    __builtin_amdgcn_s_setprio(1);                                   \
    MFMA_Q(1, 0); MFMA_Q(1, 1);                                      \
    __builtin_amdgcn_s_setprio(0);                                   \
    BAR();                                                           \
  }

// Stage one half-tile (128 rows x 64 cols fp16 = 16 KB) via global_load_lds.
// LDS dest linear; global src pre-inverse-swizzled (rule #21).
__device__ __forceinline__ void stage_half(
    const u16* __restrict__ g, int ld, int rowbase, int kbase,
    char* ldshalf, int wid, int lane)
{
#pragma unroll
    for (int s = 0; s < 2; ++s) {
        const int slot = s * 512 + wid * 64 + lane;
        const int r = slot >> 3;
        const int cb = ((slot & 7) << 4) ^ ((r & 7) << 4);
        const u16* gp = g + (size_t)(rowbase + r) * ld + kbase + (cb >> 1);
        __builtin_amdgcn_global_load_lds(
            (const __attribute__((address_space(1))) void*)gp,
            (__attribute__((address_space(3))) void*)(ldshalf + s * 8192 + wid * 1024),
            16, 0, 0);
    }
}

// mode 0: f32 store to Cv (ldc). mode 3: n0<1024 -> f32 phase to Cv;
// n0>=1024 -> fp16 v to Vv (ld 1024, col-1024).
__global__ __launch_bounds__(512, 2) void gemm_mfma256(
    const u16* __restrict__ A, int lda, const u16* __restrict__ W, int ldw,
    void* __restrict__ Cv, int ldc, void* __restrict__ Vv, int K, int mode)
{
    __shared__ __align__(16) char lds[131072];

    const int tid  = threadIdx.x;
    const int lane = tid & 63;
    const int wid  = tid >> 6;      // 0..7
    const int wm   = wid >> 2;      // 0..1
    const int wn   = wid & 3;       // 0..3
    const int l15  = lane & 15;
    const int hib  = (lane >> 4) << 4;

    // XCD-aware swizzle (gridDim.y == 64 for all our GEMMs; total % 8 == 0):
    // xcd = flat&7; within XCD: bx-major so the B panel stays L2-hot.
    const int flat = blockIdx.y * gridDim.x + blockIdx.x;
    const int xcd  = flat & 7;
    const int c    = flat >> 3;
    const int bx   = c >> 3;
    const int byl  = c & 7;
    const int m0   = (xcd * 8 + byl) * 256;
    const int n0   = bx * 256;

    const int NK2 = K / (2 * GBK);

    f32x4 acc[8][4] = {};
    s16x8 aR[4][2], bR[4][2];

    const int Xl = (l15 & 7) << 4;
    unsigned bA[2][2], bB[2][2];
#pragma unroll
    for (int p2 = 0; p2 < 2; ++p2)
#pragma unroll
        for (int ks = 0; ks < 2; ++ks) {
            bA[p2][ks] = lds_addr(lds) + p2 * 65536 +
                         (wm * 128 + l15) * 128 + ((ks * 64 + hib) ^ Xl);
            bB[p2][ks] = lds_addr(lds) + p2 * 65536 + 32768 +
                         (wn * 64 + l15) * 128 + ((ks * 64 + hib) ^ Xl);
        }

    auto STAGE_A = [&](int kt, int buf, int h) {
        stage_half(A, lda, m0 + h * 128, kt * GBK,
                   (char*)lds + buf * 65536 + h * 16384, wid, lane);
    };
    auto STAGE_B = [&](int kt, int buf, int h) {
        stage_half(W, ldw, n0 + h * 128, kt * GBK,
                   (char*)lds + buf * 65536 + 32768 + h * 16384, wid, lane);
    };

    // prologue: ktile0 -> buf0 (B,A); ktile1 -> buf1 (B)
    STAGE_B(0, 0, 0); STAGE_B(0, 0, 1);
    STAGE_A(0, 0, 0); STAGE_A(0, 0, 1);
    STAGE_B(1, 1, 0); STAGE_B(1, 1, 1);
    VMCNT4();
    BAR();

    for (int t = 0; t < NK2; ++t) {
        const bool gm = (t < NK2 - 1);
        PHASE_GROUP(0)
        PHASE_GROUP(1)
    }

    // epilogue: C/D layout col=lane&15, row=(lane>>4)*4+r per 16x16 frag
    float* Cf = (float*)Cv;
    u16*   Vh = (u16*)Vv;
    const bool isPhase = (mode == 0) || (n0 < 1024);
#pragma unroll
    for (int m = 0; m < 8; ++m) {
#pragma unroll
        for (int n = 0; n < 4; ++n) {
            const int r0  = m0 + wm * 128 + m * 16 + ((lane >> 4) << 2);
            const int col = n0 + wn * 64 + n * 16 + l15;
#pragma unroll
            for (int r = 0; r < 4; ++r) {
                const float val = acc[m][n][r];
                if (isPhase) {
                    Cf[(size_t)(r0 + r) * ldc + col] = val;
                } else {
                    Vh[(size_t)(r0 + r) * 1024 + (col - 1024)] = f2h(val);
                }
            }
        }
    }
}

// ---------------- scan ----------------
__device__ __forceinline__ void rotor_sincos(int t, double fd, float* sr, float* cr)
{
    const double twopi = 6.283185307179586;
    const double inv2pi = 0.15915494309189535;
    double ang = (double)t * fd;
    double n = rint(ang * inv2pi);
    float red = (float)(ang - n * twopi);
    __sincosf(red, sr, cr);
}

__global__ __launch_bounds__(256) void scan_pass1(
    const u16* __restrict__ vArr, const float* __restrict__ phase,
    float* __restrict__ cs)
{
    int gw = (blockIdx.x * 256 + threadIdx.x) >> 6;
    int d = threadIdx.x & 63;
    int c = gw & (NCH - 1);
    int h = (gw >> 7) & (H_N - 1);
    int b = gw >> 11;

    double fd = 6.283185307179586 * ((double)(h + 1) / 16.0)
              * pow(10000.0, -(double)d / 64.0);

    int t0 = c * CH;
    size_t base = ((size_t)b * T_LEN + t0) * HD + (size_t)h * D_N + d;

    float cr, sr;
    rotor_sincos(t0, fd, &sr, &cr);
    float cf, sf;
    sincosf((float)fd, &sf, &cf);

    float cp = 0.f, spv = 0.f;
    if (t0 > 0) {
        float thp = phase[base - HD];
        __sincosf(thp, &spv, &cp);
    }

    float sp_re = 0.f, sp_im = 0.f, sa_re = 0.f, sa_im = 0.f;
    for (int i = 0; i < CH; ++i) {
        size_t idx = base + (size_t)i * HD;
        float v = h2f(vArr[idx]);
        float th = phase[idx];
        sp_re = fmaf(v, cr, sp_re);
        sp_im = fmaf(v, sr, sp_im);
        sa_re = fmaf(v, cp, sa_re);
        sa_im = fmaf(-v, spv, sa_im);
        __sincosf(th, &spv, &cp);
        float nc = fmaf(cr, cf, -sr * sf);
        float ns = fmaf(sr, cf,  cr * sf);
        cr = nc; sr = ns;
    }

    const size_t NT = (size_t)B_SZ * H_N * NCH * D_N;
    size_t ci = (size_t)gw * D_N + d;
    cs[ci] = sp_re;
    cs[NT + ci] = sp_im;
    cs[2 * NT + ci] = sa_re;
    cs[3 * NT + ci] = sa_im;
}

__global__ void scan_pass2(float* __restrict__ cs)
{
    int tid = blockIdx.x * blockDim.x + threadIdx.x;
    if (tid >= B_SZ * H_N * D_N) return;
    int d = tid & 63;
    int bh = tid >> 6;
    size_t base = (size_t)bh * NCH * D_N + d;
    const size_t NT = (size_t)B_SZ * H_N * NCH * D_N;
    float r0 = 0.f, r1 = 0.f, r2 = 0.f, r3 = 0.f;
    for (int c = 0; c < NCH; ++c) {
        size_t i = base + (size_t)c * D_N;
        float a = cs[i], b2 = cs[NT + i], c2 = cs[2 * NT + i], d2 = cs[3 * NT + i];
        cs[i] = r0; cs[NT + i] = r1; cs[2 * NT + i] = r2; cs[3 * NT + i] = r3;
        r0 += a; r1 += b2; r2 += c2; r3 += d2;
    }
}

__global__ __launch_bounds__(256) void scan_pass3(
    const u16* __restrict__ vArr, const float* __restrict__ phase,
    const float* __restrict__ cs, const float* __restrict__ gate,
    u16* __restrict__ y)
{
    int gw = (blockIdx.x * 256 + threadIdx.x) >> 6;
    int d = threadIdx.x & 63;
    int c = gw & (NCH - 1);
    int h = (gw >> 7) & (H_N - 1);
    int b = gw >> 11;

    double fd = 6.283185307179586 * ((double)(h + 1) / 16.0)
              * pow(10000.0, -(double)d / 64.0);
    float g0 = gate[h * 2 + 0];
    float g1 = gate[h * 2 + 1];

    int t0 = c * CH;
    size_t base = ((size_t)b * T_LEN + t0) * HD + (size_t)h * D_N + d;

    const size_t NT = (size_t)B_SZ * H_N * NCH * D_N;
    size_t ci = (size_t)gw * D_N + d;
    float ap_re = cs[ci];
    float ap_im = cs[NT + ci];
    float aa_re = cs[2 * NT + ci];
    float aa_im = cs[3 * NT + ci];

    float cr, sr;
    rotor_sincos(t0, fd, &sr, &cr);
    float cf, sf;
    sincosf((float)fd, &sf, &cf);

    float cp = 0.f, spv = 0.f;
    if (t0 > 0) {
        float thp = phase[base - HD];
        __sincosf(thp, &spv, &cp);
    }

    for (int i = 0; i < CH; ++i) {
        int t = t0 + i;
        size_t idx = base + (size_t)i * HD;
        float v = h2f(vArr[idx]);
        float th = phase[idx];
        ap_re = fmaf(v, cr, ap_re);
        ap_im = fmaf(v, sr, ap_im);
        aa_re = fmaf(v, cp, aa_re);
        aa_im = fmaf(-v, spv, aa_im);
        float op = fmaf(ap_re, cr, ap_im * sr);
        float ck, sk;
        __sincosf(th, &sk, &ck);
        float oa = fmaf(aa_re, ck, -aa_im * sk);
        float sc = rsqrtf((float)(t + 1));
        y[idx] = f2h((g0 * op + g1 * oa) * sc);
        cp = ck; spv = sk;
        float nc = fmaf(cr, cf, -sr * sf);
        float ns = fmaf(sr, cf,  cr * sf);
        cr = nc; sr = ns;
    }
}

// ---------------- launch ----------------
extern "C" void kernel_launch(void* const* d_in, const int* in_sizes, int n_in,
                              void* d_out, int out_size, void* d_ws, size_t ws_size,
                              hipStream_t stream)
{
    const float* x    = (const float*)d_in[0];
    const float* Wk   = (const float*)d_in[1];
    const float* Wv   = (const float*)d_in[2];
    const float* Wo   = (const float*)d_in[3];
    const float* gate = (const float*)d_in[4];
    float* out = (float*)d_out;

    // phase lives in d_out (dead before the final GEMM overwrites it).
    float* phase = (float*)d_out;

    // ws layout (MiB offsets):
    //   0  : xh  [16384][1024] fp16 = 32   -- yb aliases it after merged GEMM
    //   32 : vb  [16384][1024] fp16 = 32
    //   64 : cs  4 * 2*16*128*64 f32 = 4
    //   68 : Wkv [2048][1024] fp16  = 4    (10Wk | Wv)
    //   72 : Wob [1024][1024] fp16  = 2    total 74 MiB
    char* wsb = (char*)d_ws;
    u16*   xh  = (u16*)wsb;
    u16*   yb  = (u16*)wsb;                       // alias: xh dead after merged GEMM
    u16*   vb  = (u16*)(wsb + (32ull << 20));
    float* cs  = (float*)(wsb + (64ull << 20));
    u16*   Wkv = (u16*)(wsb + (68ull << 20));
    u16*   Wob = (u16*)(wsb + (72ull << 20));

    hipLaunchKernelGGL(conv_x_h, dim3(16384), dim3(256), 0, stream, x, xh);
    hipLaunchKernelGGL(conv_wkv, dim3(2048), dim3(256), 0, stream, Wk, Wv, Wkv);
    hipLaunchKernelGGL(conv_w,   dim3(1024), dim3(256), 0, stream, Wo, Wob);

    const dim3 gblk(512);

    // [phase | v] = xh @ [10Wk | Wv]^T   (M=16384, N=2048, K=1024)
    hipLaunchKernelGGL(gemm_mfma256, dim3(8, 64), gblk, 0, stream,
                       xh, 1024, Wkv, 1024, (void*)phase, HD, (void*)vb, 1024, 3);

    const int waves = B_SZ * H_N * NCH;   // 4096
    hipLaunchKernelGGL(scan_pass1, dim3(waves / 4), dim3(256), 0, stream, vb, phase, cs);
    hipLaunchKernelGGL(scan_pass2, dim3(8), dim3(256), 0, stream, cs);
    hipLaunchKernelGGL(scan_pass3, dim3(waves / 4), dim3(256), 0, stream, vb, phase, cs, gate, yb);

    // out = yb @ Wo^T   (M=16384, N=1024, K=1024; overwrites phase in d_out)
    hipLaunchKernelGGL(gemm_mfma256, dim3(4, 64), gblk, 0, stream,
                       yb, 1024, Wob, 1024, (void*)out, HD, (void*)0, 1024, 0);
}

// Round 8
// 186.704 us; speedup vs baseline: 6.9130x; 1.0215x over previous
//
#include <hip/hip_runtime.h>
#include <math.h>

// HoloAttentionV2 on MI355X (gfx950).
// fp16 MFMA GEMMs (single K=1024 phase pass; no bf16 hi/lo split needed).
// [10Wk|Wv] GEMM M-split into two 256-block launches (1 block/CU each),
// mixed f32/fp16 epilogue; out GEMM 256 blocks. 256x256 tile, 4-phase
// schedule, XCD swizzle (parametric), LDS XOR swizzle, counted vmcnt, setprio.
// 3-pass chunked complex scan. Shapes: B=2, T=8192, H=16, D=64, HD=DM=1024.

#define B_SZ 2
#define T_LEN 8192
#define H_N 16
#define D_N 64
#define HD 1024
#define DM 1024

#define NCH 128                 // chunks per chain
#define CH (T_LEN / NCH)        // 64 steps per chunk

typedef unsigned short u16;
typedef __attribute__((ext_vector_type(4))) unsigned short u16x4;
typedef __attribute__((ext_vector_type(8))) short s16x8;     // 16B LDS payload
typedef __attribute__((ext_vector_type(8))) _Float16 f16x8;  // MFMA operand
typedef __attribute__((ext_vector_type(4))) float f32x4;

__device__ __forceinline__ u16 f2h(float f) {
    return __builtin_bit_cast(u16, (_Float16)f);    // v_cvt_f16_f32, RNE
}
__device__ __forceinline__ float h2f(u16 h) {
    return (float)__builtin_bit_cast(_Float16, h);
}

// ---------------- conversion kernels ----------------
__global__ __launch_bounds__(256) void conv_x_h(
    const float* __restrict__ x, u16* __restrict__ xh)
{
    size_t i = ((size_t)blockIdx.x * 256 + threadIdx.x) * 4;
    float4 v = *reinterpret_cast<const float4*>(&x[i]);
    u16x4 o = { f2h(v.x), f2h(v.y), f2h(v.z), f2h(v.w) };
    *reinterpret_cast<u16x4*>(&xh[i]) = o;
}

// Wkv rows 0..1023 = 10*Wk, rows 1024..2047 = Wv  (fp16)
__global__ __launch_bounds__(256) void conv_wkv(
    const float* __restrict__ Wk, const float* __restrict__ Wv,
    u16* __restrict__ Wkv)
{
    size_t i = ((size_t)blockIdx.x * 256 + threadIdx.x) * 4;  // Wkv elem index
    int r = (int)(i >> 10);
    size_t src = (i & (1024 * 1024 - 1));
    float4 v;
    float s;
    if (r < 1024) { v = *reinterpret_cast<const float4*>(&Wk[i]); s = 10.f; }
    else          { v = *reinterpret_cast<const float4*>(&Wv[src]); s = 1.f; }
    u16x4 o = { f2h(s * v.x), f2h(s * v.y), f2h(s * v.z), f2h(s * v.w) };
    *reinterpret_cast<u16x4*>(&Wkv[i]) = o;
}

__global__ __launch_bounds__(256) void conv_w(
    const float* __restrict__ W, u16* __restrict__ Wb)
{
    size_t i = ((size_t)blockIdx.x * 256 + threadIdx.x) * 4;
    float4 v = *reinterpret_cast<const float4*>(&W[i]);
    u16x4 o = { f2h(v.x), f2h(v.y), f2h(v.z), f2h(v.w) };
    *reinterpret_cast<u16x4*>(&Wb[i]) = o;
}

// ---------------- 256x256 4-phase fp16 MFMA GEMM ----------------
// C[m,n] = sum_k A[m,k] * W[n,k]. 512 threads = 8 waves (2M x 4N),
// per-wave 128x64 output = 8x4 frags of 16x16. BK=64, double-buffered LDS
// (128 KiB): buf b at b*65536: A[256][64] then B[256][64], fp16,
// XOR-swizzled: byte_in_row ^= (row&7)<<4.
#define GBK 64

#define BAR()     asm volatile("s_barrier" ::: "memory")
#define VMCNT4()  asm volatile("s_waitcnt vmcnt(4)" ::: "memory")
#define VMCNT0()  asm volatile("s_waitcnt vmcnt(0)" ::: "memory")
#define LGKM8PRE() asm volatile("s_waitcnt lgkmcnt(8)" ::: "memory")
#define LGKM0_SB() do { asm volatile("s_waitcnt lgkmcnt(0)" ::: "memory"); \
                        __builtin_amdgcn_sched_barrier(0); } while (0)

template <int IMM>
__device__ __forceinline__ s16x8 dsr(unsigned base) {
    s16x8 r;
    asm volatile("ds_read_b128 %0, %1 offset:%2"
                 : "=v"(r) : "v"(base), "n"(IMM));
    return r;
}

__device__ __forceinline__ unsigned lds_addr(const void* p) {
    return (unsigned)(uintptr_t)(const __attribute__((address_space(3))) void*)p;
}

// 16 fp16 MFMA (caller wraps clusters with setprio)
#define MFMA_Q(mh, nh)                                               \
  {                                                                  \
    _Pragma("unroll")                                                \
    for (int ks_ = 0; ks_ < 2; ++ks_)                                \
      _Pragma("unroll")                                              \
      for (int m_ = 0; m_ < 4; ++m_)                                 \
        _Pragma("unroll")                                            \
        for (int n_ = 0; n_ < 2; ++n_)                               \
          acc[(mh)*4 + m_][(nh)*2 + n_] =                            \
            __builtin_amdgcn_mfma_f32_16x16x32_f16(                  \
              __builtin_bit_cast(f16x8, aR[m_][ks_]),                \
              __builtin_bit_cast(f16x8, bR[(nh)*2 + n_][ks_]),       \
              acc[(mh)*4 + m_][(nh)*2 + n_], 0, 0, 0);               \
  }

// A rows (8 of wave tile, offset ofs = 0 for rows 0-63, 8192 for rows 64-127)
#define RD_A(ph, ofs)                                                          \
  aR[0][0]=dsr<(ofs)+0>(bA[ph][0]);    aR[1][0]=dsr<(ofs)+2048>(bA[ph][0]);    \
  aR[2][0]=dsr<(ofs)+4096>(bA[ph][0]); aR[3][0]=dsr<(ofs)+6144>(bA[ph][0]);    \
  aR[0][1]=dsr<(ofs)+0>(bA[ph][1]);    aR[1][1]=dsr<(ofs)+2048>(bA[ph][1]);    \
  aR[2][1]=dsr<(ofs)+4096>(bA[ph][1]); aR[3][1]=dsr<(ofs)+6144>(bA[ph][1]);
#define RD_B01(ph)                                                             \
  bR[0][0]=dsr<0>(bB[ph][0]);    bR[1][0]=dsr<2048>(bB[ph][0]);                \
  bR[0][1]=dsr<0>(bB[ph][1]);    bR[1][1]=dsr<2048>(bB[ph][1]);
#define RD_B23(ph)                                                             \
  bR[2][0]=dsr<4096>(bB[ph][0]); bR[3][0]=dsr<6144>(bB[ph][0]);                \
  bR[2][1]=dsr<4096>(bB[ph][1]); bR[3][1]=dsr<6144>(bB[ph][1]);

// One K-tile, 2 phases. ph = buffer. Race audit: B-stage (P2 -> buf[ph].B)
// after P1's lgkm0 drained this group's B reads; A-stage (P1 -> buf[ph^1].A)
// after prev group's P2 lgkm0 drained its A-bottom reads. vmcnt(4) at P2
// drains next buffer's A+B exactly, keeps following B half-pair in flight.
#define PHASE_GROUP(ph)                                              \
  {                                                                  \
    RD_A(ph, 0); RD_B01(ph); RD_B23(ph);                             \
    LGKM8PRE();                                                      \
    if ((ph) == 0)    { STAGE_A(2*t+1, 1, 0); STAGE_A(2*t+1, 1, 1); }\
    else if (gm)      { STAGE_A(2*t+2, 0, 0); STAGE_A(2*t+2, 0, 1); }\
    BAR(); LGKM0_SB();                                               \
    __builtin_amdgcn_s_setprio(1);                                   \
    MFMA_Q(0, 0); MFMA_Q(0, 1);                                      \
    __builtin_amdgcn_s_setprio(0);                                   \
    BAR();                                                           \
    RD_A(ph, 8192);                                                  \
    if (gm) { STAGE_B(2*t+2+(ph), (ph), 0);                          \
              STAGE_B(2*t+2+(ph), (ph), 1); VMCNT4(); }              \
    else    { VMCNT0(); }                                            \
    BAR(); LGKM0_SB();                                               \
    __builtin_amdgcn_s_setprio(1);                                   \
    MFMA_Q(1, 0); MFMA_Q(1, 1);                                      \
    __builtin_amdgcn_s_setprio(0);                                   \
    BAR();                                                           \
  }

// Stage one half-tile (128 rows x 64 cols fp16 = 16 KB) via global_load_lds.
// LDS dest linear; global src pre-inverse-swizzled (rule #21).
__device__ __forceinline__ void stage_half(
    const u16* __restrict__ g, int ld, int rowbase, int kbase,
    char* ldshalf, int wid, int lane)
{
#pragma unroll
    for (int s = 0; s < 2; ++s) {
        const int slot = s * 512 + wid * 64 + lane;
        const int r = slot >> 3;
        const int cb = ((slot & 7) << 4) ^ ((r & 7) << 4);
        const u16* gp = g + (size_t)(rowbase + r) * ld + kbase + (cb >> 1);
        __builtin_amdgcn_global_load_lds(
            (const __attribute__((address_space(1))) void*)gp,
            (__attribute__((address_space(3))) void*)(ldshalf + s * 8192 + wid * 1024),
            16, 0, 0);
    }
}

// mode 0: f32 store to Cv (ldc). mode 3: n0<1024 -> f32 phase to Cv;
// n0>=1024 -> fp16 v to Vv (ld 1024, col-1024).
// Swizzle: xcd = flat&7; per-XCD byl_cnt = 1<<bshift m-tiles; bx-major order
// so the small A panel set stays L2-resident across B columns.
__global__ __launch_bounds__(512, 2) void gemm_mfma256(
    const u16* __restrict__ A, int lda, const u16* __restrict__ W, int ldw,
    void* __restrict__ Cv, int ldc, void* __restrict__ Vv, int K, int mode,
    int m_base, int bshift)
{
    __shared__ __align__(16) char lds[131072];

    const int tid  = threadIdx.x;
    const int lane = tid & 63;
    const int wid  = tid >> 6;      // 0..7
    const int wm   = wid >> 2;      // 0..1
    const int wn   = wid & 3;       // 0..3
    const int l15  = lane & 15;
    const int hib  = (lane >> 4) << 4;

    const int flat = blockIdx.y * gridDim.x + blockIdx.x;
    const int xcd  = flat & 7;
    const int c    = flat >> 3;
    const int byl  = c & ((1 << bshift) - 1);
    const int bx   = c >> bshift;
    const int m0   = ((xcd << bshift) + byl) * 256 + m_base;
    const int n0   = bx * 256;

    const int NK2 = K / (2 * GBK);

    f32x4 acc[8][4] = {};
    s16x8 aR[4][2], bR[4][2];

    const int Xl = (l15 & 7) << 4;
    unsigned bA[2][2], bB[2][2];
#pragma unroll
    for (int p2 = 0; p2 < 2; ++p2)
#pragma unroll
        for (int ks = 0; ks < 2; ++ks) {
            bA[p2][ks] = lds_addr(lds) + p2 * 65536 +
                         (wm * 128 + l15) * 128 + ((ks * 64 + hib) ^ Xl);
            bB[p2][ks] = lds_addr(lds) + p2 * 65536 + 32768 +
                         (wn * 64 + l15) * 128 + ((ks * 64 + hib) ^ Xl);
        }

    auto STAGE_A = [&](int kt, int buf, int h) {
        stage_half(A, lda, m0 + h * 128, kt * GBK,
                   (char*)lds + buf * 65536 + h * 16384, wid, lane);
    };
    auto STAGE_B = [&](int kt, int buf, int h) {
        stage_half(W, ldw, n0 + h * 128, kt * GBK,
                   (char*)lds + buf * 65536 + 32768 + h * 16384, wid, lane);
    };

    // prologue: ktile0 -> buf0 (B,A); ktile1 -> buf1 (B)
    STAGE_B(0, 0, 0); STAGE_B(0, 0, 1);
    STAGE_A(0, 0, 0); STAGE_A(0, 0, 1);
    STAGE_B(1, 1, 0); STAGE_B(1, 1, 1);
    VMCNT4();
    BAR();

    for (int t = 0; t < NK2; ++t) {
        const bool gm = (t < NK2 - 1);
        PHASE_GROUP(0)
        PHASE_GROUP(1)
    }

    // epilogue: C/D layout col=lane&15, row=(lane>>4)*4+r per 16x16 frag
    float* Cf = (float*)Cv;
    u16*   Vh = (u16*)Vv;
    const bool isPhase = (mode == 0) || (n0 < 1024);
#pragma unroll
    for (int m = 0; m < 8; ++m) {
#pragma unroll
        for (int n = 0; n < 4; ++n) {
            const int r0  = m0 + wm * 128 + m * 16 + ((lane >> 4) << 2);
            const int col = n0 + wn * 64 + n * 16 + l15;
#pragma unroll
            for (int r = 0; r < 4; ++r) {
                const float val = acc[m][n][r];
                if (isPhase) {
                    Cf[(size_t)(r0 + r) * ldc + col] = val;
                } else {
                    Vh[(size_t)(r0 + r) * 1024 + (col - 1024)] = f2h(val);
                }
            }
        }
    }
}

// ---------------- scan ----------------
__device__ __forceinline__ void rotor_sincos(int t, double fd, float* sr, float* cr)
{
    const double twopi = 6.283185307179586;
    const double inv2pi = 0.15915494309189535;
    double ang = (double)t * fd;
    double n = rint(ang * inv2pi);
    float red = (float)(ang - n * twopi);
    __sincosf(red, sr, cr);
}

__global__ __launch_bounds__(256) void scan_pass1(
    const u16* __restrict__ vArr, const float* __restrict__ phase,
    float* __restrict__ cs)
{
    int gw = (blockIdx.x * 256 + threadIdx.x) >> 6;
    int d = threadIdx.x & 63;
    int c = gw & (NCH - 1);
    int h = (gw >> 7) & (H_N - 1);
    int b = gw >> 11;

    double fd = 6.283185307179586 * ((double)(h + 1) / 16.0)
              * pow(10000.0, -(double)d / 64.0);

    int t0 = c * CH;
    size_t base = ((size_t)b * T_LEN + t0) * HD + (size_t)h * D_N + d;

    float cr, sr;
    rotor_sincos(t0, fd, &sr, &cr);
    float cf, sf;
    sincosf((float)fd, &sf, &cf);

    float cp = 0.f, spv = 0.f;
    if (t0 > 0) {
        float thp = phase[base - HD];
        __sincosf(thp, &spv, &cp);
    }

    float sp_re = 0.f, sp_im = 0.f, sa_re = 0.f, sa_im = 0.f;
    for (int i = 0; i < CH; ++i) {
        size_t idx = base + (size_t)i * HD;
        float v = h2f(vArr[idx]);
        float th = phase[idx];
        sp_re = fmaf(v, cr, sp_re);
        sp_im = fmaf(v, sr, sp_im);
        sa_re = fmaf(v, cp, sa_re);
        sa_im = fmaf(-v, spv, sa_im);
        __sincosf(th, &spv, &cp);
        float nc = fmaf(cr, cf, -sr * sf);
        float ns = fmaf(sr, cf,  cr * sf);
        cr = nc; sr = ns;
    }

    const size_t NT = (size_t)B_SZ * H_N * NCH * D_N;
    size_t ci = (size_t)gw * D_N + d;
    cs[ci] = sp_re;
    cs[NT + ci] = sp_im;
    cs[2 * NT + ci] = sa_re;
    cs[3 * NT + ci] = sa_im;
}

__global__ void scan_pass2(float* __restrict__ cs)
{
    int tid = blockIdx.x * blockDim.x + threadIdx.x;
    if (tid >= B_SZ * H_N * D_N) return;
    int d = tid & 63;
    int bh = tid >> 6;
    size_t base = (size_t)bh * NCH * D_N + d;
    const size_t NT = (size_t)B_SZ * H_N * NCH * D_N;
    float r0 = 0.f, r1 = 0.f, r2 = 0.f, r3 = 0.f;
    for (int c = 0; c < NCH; ++c) {
        size_t i = base + (size_t)c * D_N;
        float a = cs[i], b2 = cs[NT + i], c2 = cs[2 * NT + i], d2 = cs[3 * NT + i];
        cs[i] = r0; cs[NT + i] = r1; cs[2 * NT + i] = r2; cs[3 * NT + i] = r3;
        r0 += a; r1 += b2; r2 += c2; r3 += d2;
    }
}

__global__ __launch_bounds__(256) void scan_pass3(
    const u16* __restrict__ vArr, const float* __restrict__ phase,
    const float* __restrict__ cs, const float* __restrict__ gate,
    u16* __restrict__ y)
{
    int gw = (blockIdx.x * 256 + threadIdx.x) >> 6;
    int d = threadIdx.x & 63;
    int c = gw & (NCH - 1);
    int h = (gw >> 7) & (H_N - 1);
    int b = gw >> 11;

    double fd = 6.283185307179586 * ((double)(h + 1) / 16.0)
              * pow(10000.0, -(double)d / 64.0);
    float g0 = gate[h * 2 + 0];
    float g1 = gate[h * 2 + 1];

    int t0 = c * CH;
    size_t base = ((size_t)b * T_LEN + t0) * HD + (size_t)h * D_N + d;

    const size_t NT = (size_t)B_SZ * H_N * NCH * D_N;
    size_t ci = (size_t)gw * D_N + d;
    float ap_re = cs[ci];
    float ap_im = cs[NT + ci];
    float aa_re = cs[2 * NT + ci];
    float aa_im = cs[3 * NT + ci];

    float cr, sr;
    rotor_sincos(t0, fd, &sr, &cr);
    float cf, sf;
    sincosf((float)fd, &sf, &cf);

    float cp = 0.f, spv = 0.f;
    if (t0 > 0) {
        float thp = phase[base - HD];
        __sincosf(thp, &spv, &cp);
    }

    for (int i = 0; i < CH; ++i) {
        int t = t0 + i;
        size_t idx = base + (size_t)i * HD;
        float v = h2f(vArr[idx]);
        float th = phase[idx];
        ap_re = fmaf(v, cr, ap_re);
        ap_im = fmaf(v, sr, ap_im);
        aa_re = fmaf(v, cp, aa_re);
        aa_im = fmaf(-v, spv, aa_im);
        float op = fmaf(ap_re, cr, ap_im * sr);
        float ck, sk;
        __sincosf(th, &sk, &ck);
        float oa = fmaf(aa_re, ck, -aa_im * sk);
        float sc = rsqrtf((float)(t + 1));
        y[idx] = f2h((g0 * op + g1 * oa) * sc);
        cp = ck; spv = sk;
        float nc = fmaf(cr, cf, -sr * sf);
        float ns = fmaf(sr, cf,  cr * sf);
        cr = nc; sr = ns;
    }
}

// ---------------- launch ----------------
extern "C" void kernel_launch(void* const* d_in, const int* in_sizes, int n_in,
                              void* d_out, int out_size, void* d_ws, size_t ws_size,
                              hipStream_t stream)
{
    const float* x    = (const float*)d_in[0];
    const float* Wk   = (const float*)d_in[1];
    const float* Wv   = (const float*)d_in[2];
    const float* Wo   = (const float*)d_in[3];
    const float* gate = (const float*)d_in[4];
    float* out = (float*)d_out;

    // phase lives in d_out (dead before the final GEMM overwrites it).
    float* phase = (float*)d_out;

    // ws layout (MiB offsets):
    //   0  : xh  [16384][1024] fp16 = 32   -- yb aliases it after merged GEMM
    //   32 : vb  [16384][1024] fp16 = 32
    //   64 : cs  4 * 2*16*128*64 f32 = 4
    //   68 : Wkv [2048][1024] fp16  = 4    (10Wk | Wv)
    //   72 : Wob [1024][1024] fp16  = 2    total 74 MiB
    char* wsb = (char*)d_ws;
    u16*   xh  = (u16*)wsb;
    u16*   yb  = (u16*)wsb;                       // alias: xh dead after merged GEMM
    u16*   vb  = (u16*)(wsb + (32ull << 20));
    float* cs  = (float*)(wsb + (64ull << 20));
    u16*   Wkv = (u16*)(wsb + (68ull << 20));
    u16*   Wob = (u16*)(wsb + (72ull << 20));

    hipLaunchKernelGGL(conv_x_h, dim3(16384), dim3(256), 0, stream, x, xh);
    hipLaunchKernelGGL(conv_wkv, dim3(2048), dim3(256), 0, stream, Wk, Wv, Wkv);
    hipLaunchKernelGGL(conv_w,   dim3(1024), dim3(256), 0, stream, Wo, Wob);

    const dim3 gblk(512);

    // [phase | v] = xh @ [10Wk | Wv]^T  (M=16384, N=2048, K=1024),
    // M-split into two 256-block launches (1 block/CU each).
    hipLaunchKernelGGL(gemm_mfma256, dim3(8, 32), gblk, 0, stream,
                       xh, 1024, Wkv, 1024, (void*)phase, HD, (void*)vb, 1024, 3,
                       0, 2);
    hipLaunchKernelGGL(gemm_mfma256, dim3(8, 32), gblk, 0, stream,
                       xh, 1024, Wkv, 1024, (void*)phase, HD, (void*)vb, 1024, 3,
                       8192, 2);

    const int waves = B_SZ * H_N * NCH;   // 4096
    hipLaunchKernelGGL(scan_pass1, dim3(waves / 4), dim3(256), 0, stream, vb, phase, cs);
    hipLaunchKernelGGL(scan_pass2, dim3(8), dim3(256), 0, stream, cs);
    hipLaunchKernelGGL(scan_pass3, dim3(waves / 4), dim3(256), 0, stream, vb, phase, cs, gate, yb);

    // out = yb @ Wo^T   (M=16384, N=1024, K=1024; overwrites phase in d_out)
    hipLaunchKernelGGL(gemm_mfma256, dim3(4, 64), gblk, 0, stream,
                       yb, 1024, Wob, 1024, (void*)out, HD, (void*)0, 1024, 0,
                       0, 3);
}